// Round 15
// baseline (209.906 us; speedup 1.0000x reference)
//
#include <hip/hip_runtime.h>

typedef short bf16x8 __attribute__((ext_vector_type(8)));
typedef float f32x4 __attribute__((ext_vector_type(4)));
typedef unsigned short u16x8 __attribute__((ext_vector_type(8)));

#define NB 4
#define SQ 2048
#define EM 512
#define NH 8
#define DHD 64
// 1/sqrt(DH) * log2(e): Q pre-scaled so softmax uses exp2
#define QSCALE 0.1803368801111731f

__device__ __forceinline__ unsigned short f2bf(float x) {
  unsigned u = __float_as_uint(x);
  u += 0x7FFFu + ((u >> 16) & 1u);
  return (unsigned short)(u >> 16);
}

__device__ __forceinline__ int sw8(int row, int col8) { return col8 ^ ((row & 7) << 3); }

// async global->LDS, 16B/lane; LDS dest = wave-uniform base + lane*16 (linear).
// Swizzled storage achieved by pre-swizzling the per-lane GLOBAL source address.
__device__ __forceinline__ void glds16(const void* g, void* l) {
  __builtin_amdgcn_global_load_lds(
      (const __attribute__((address_space(1))) void*)g,
      (__attribute__((address_space(3))) void*)l, 16, 0, 0);
}

// ---------------- fused fp32 -> bf16 convert (all 4 weight tensors) ----------------
__global__ __launch_bounds__(256) void f2bf4_kernel(
    const float* __restrict__ w0, const float* __restrict__ w1,
    const float* __restrict__ w2, const float* __restrict__ w3,
    unsigned short* __restrict__ o0, unsigned short* __restrict__ o1,
    unsigned short* __restrict__ o2, unsigned short* __restrict__ o3) {
  int i = (blockIdx.x * 256 + threadIdx.x) * 8;
  const float* src;
  unsigned short* dst;
  int off;
  if (i < 786432) { src = w0; dst = o0; off = i; }
  else if (i < 1048576) { src = w1; dst = o1; off = i - 786432; }
  else if (i < 1310720) { src = w2; dst = o2; off = i - 1048576; }
  else { src = w3; dst = o3; off = i - 1310720; }
  f32x4 a = *(const f32x4*)(src + off);
  f32x4 b = *(const f32x4*)(src + off + 4);
  u16x8 o;
#pragma unroll
  for (int j = 0; j < 4; ++j) { o[j] = f2bf(a[j]); o[j + 4] = f2bf(b[j]); }
  *(u16x8*)(dst + off) = o;
}

// ---------------- LayerNorm (row = E=512), fp32 in -> bf16 out ----------------
__global__ __launch_bounds__(256) void ln_kernel(const float* __restrict__ x,
                                                 const float* __restrict__ g,
                                                 const float* __restrict__ bb,
                                                 unsigned short* __restrict__ out) {
  int tid = threadIdx.x;
  int row = blockIdx.x * 4 + (tid >> 6);
  int lane = tid & 63;
  size_t base = (size_t)row * EM + lane * 8;
  f32x4 v0 = *(const f32x4*)(x + base);
  f32x4 v1 = *(const f32x4*)(x + base + 4);
  float s = 0.f, q = 0.f;
#pragma unroll
  for (int j = 0; j < 4; ++j) { s += v0[j] + v1[j]; q += v0[j] * v0[j] + v1[j] * v1[j]; }
#pragma unroll
  for (int m = 1; m < 64; m <<= 1) { s += __shfl_xor(s, m); q += __shfl_xor(q, m); }
  float mean = s * (1.f / EM);
  float var = q * (1.f / EM) - mean * mean;
  float rs = rsqrtf(var + 1e-5f);
  f32x4 g0 = *(const f32x4*)(g + lane * 8), g1 = *(const f32x4*)(g + lane * 8 + 4);
  f32x4 b0 = *(const f32x4*)(bb + lane * 8), b1 = *(const f32x4*)(bb + lane * 8 + 4);
  u16x8 o;
#pragma unroll
  for (int j = 0; j < 4; ++j) {
    o[j] = f2bf((v0[j] - mean) * rs * g0[j] + b0[j]);
    o[j + 4] = f2bf((v1[j] - mean) * rs * g1[j] + b1[j]);
  }
  *(u16x8*)(out + base) = o;
}

// ---------------- GEMM 64x64: dbuf LDS via global_load_lds (1 barrier/iter) ----------------
template <bool LEAKY, bool RESID, bool OUTF32, bool QKV>
__global__ __launch_bounds__(256) void gemm64(
    const unsigned short* __restrict__ A, const unsigned short* __restrict__ Bm,
    const float* __restrict__ bias, const float* __restrict__ resid,
    float* __restrict__ outf, unsigned short* __restrict__ outh,
    unsigned short* __restrict__ qo, unsigned short* __restrict__ ko,
    unsigned short* __restrict__ vo, int M, int N, int K) {
  __shared__ unsigned short As[2][64][64];
  __shared__ unsigned short Bs[2][64][64];
  int m0 = blockIdx.x * 64, n0 = blockIdx.y * 64;
  int t = threadIdx.x;
  int wv = t >> 6, ln = t & 63, lg = ln >> 4, lr = ln & 15;
  int rsub = ln >> 3;
  int csw = ((ln & 7) ^ rsub) * 8;
  f32x4 acc[4];
#pragma unroll
  for (int c = 0; c < 4; ++c)
#pragma unroll
    for (int r = 0; r < 4; ++r) acc[c][r] = 0.f;

  const unsigned short* ag0 = A + (size_t)(m0 + wv * 16 + rsub) * K + csw;
  const unsigned short* ag1 = A + (size_t)(m0 + wv * 16 + 8 + rsub) * K + csw;
  const unsigned short* bg0 = Bm + (size_t)(n0 + wv * 16 + rsub) * K + csw;
  const unsigned short* bg1 = Bm + (size_t)(n0 + wv * 16 + 8 + rsub) * K + csw;

  glds16(ag0, &As[0][wv * 16][0]);
  glds16(ag1, &As[0][wv * 16 + 8][0]);
  glds16(bg0, &Bs[0][wv * 16][0]);
  glds16(bg1, &Bs[0][wv * 16 + 8][0]);

  int nk = K >> 6;
  for (int ki = 0; ki < nk; ++ki) {
    int cur = ki & 1;
    __syncthreads();
    if (ki + 1 < nk) {
      int nb = cur ^ 1;
      int ko_ = (ki + 1) * 64;
      glds16(ag0 + ko_, &As[nb][wv * 16][0]);
      glds16(ag1 + ko_, &As[nb][wv * 16 + 8][0]);
      glds16(bg0 + ko_, &Bs[nb][wv * 16][0]);
      glds16(bg1 + ko_, &Bs[nb][wv * 16 + 8][0]);
    }
#pragma unroll
    for (int kk = 0; kk < 64; kk += 32) {
      int arw = wv * 16 + lr;
      bf16x8 af = *(const bf16x8*)&As[cur][arw][sw8(arw, kk + lg * 8)];
#pragma unroll
      for (int c = 0; c < 4; ++c) {
        int brw = c * 16 + lr;
        bf16x8 bf = *(const bf16x8*)&Bs[cur][brw][sw8(brw, kk + lg * 8)];
        acc[c] = __builtin_amdgcn_mfma_f32_16x16x32_bf16(af, bf, acc[c], 0, 0, 0);
      }
    }
  }
#pragma unroll
  for (int c = 0; c < 4; ++c) {
    int C_ = n0 + c * 16 + lr;
    float bv = bias[C_];
#pragma unroll
    for (int r = 0; r < 4; ++r) {
      int R_ = m0 + wv * 16 + lg * 4 + r;
      float v = acc[c][r] + bv;
      if (LEAKY) v = v > 0.f ? v : 0.01f * v;
      if (RESID) v += resid[(size_t)R_ * N + C_];
      if (QKV) {
        int which = C_ >> 9, f = C_ & 511, h = f >> 6, d = f & 63;
        int b_ = R_ >> 11, s_ = R_ & 2047;
        if (which == 0) {
          qo[(((size_t)b_ * NH + h) * SQ + s_) * DHD + d] = f2bf(v * QSCALE);
        } else if (which == 1) {
          ko[(((size_t)b_ * NH + h) * SQ + s_) * DHD + d] = f2bf(v);
        } else {
          vo[(((size_t)b_ * NH + h) * DHD + d) * SQ + s_] = f2bf(v);  // V^T [b,h,d,s]
        }
      } else if (OUTF32) {
        outf[(size_t)R_ * N + C_] = v;
      } else {
        outh[(size_t)R_ * N + C_] = f2bf(v);
      }
    }
  }
}

// ---------------- GEMM 128x128 (QKV only): dbuf LDS via glds, 2x2 wave quadrants ----------------
template <bool QKV>
__global__ __launch_bounds__(256) void gemm128(
    const unsigned short* __restrict__ A, const unsigned short* __restrict__ Bm,
    const float* __restrict__ bias, unsigned short* __restrict__ qo,
    unsigned short* __restrict__ ko, unsigned short* __restrict__ vo,
    int M, int N, int K) {
  __shared__ unsigned short As[2][128][64];
  __shared__ unsigned short Bs[2][128][64];
  int m0 = blockIdx.x * 128, n0 = blockIdx.y * 128;
  int t = threadIdx.x;
  int wv = t >> 6, ln = t & 63, lg = ln >> 4, lr = ln & 15;
  int wr = wv >> 1, wc = wv & 1;
  int rsub = ln >> 3;
  int csw = ((ln & 7) ^ rsub) * 8;
  f32x4 acc[4][4];
#pragma unroll
  for (int m = 0; m < 4; ++m)
#pragma unroll
    for (int n = 0; n < 4; ++n)
#pragma unroll
      for (int r = 0; r < 4; ++r) acc[m][n][r] = 0.f;

  const unsigned short* agb = A + (size_t)(m0 + wv * 8 + rsub) * K + csw;
  const unsigned short* bgb = Bm + (size_t)(n0 + wv * 8 + rsub) * K + csw;

#pragma unroll
  for (int i = 0; i < 4; ++i) {
    glds16(agb + (size_t)(i * 32) * K, &As[0][i * 32 + wv * 8][0]);
    glds16(bgb + (size_t)(i * 32) * K, &Bs[0][i * 32 + wv * 8][0]);
  }

  int nk = K >> 6;
  for (int ki = 0; ki < nk; ++ki) {
    int cur = ki & 1;
    __syncthreads();
    if (ki + 1 < nk) {
      int nb = cur ^ 1;
      int ko_ = (ki + 1) * 64;
#pragma unroll
      for (int i = 0; i < 4; ++i) {
        glds16(agb + (size_t)(i * 32) * K + ko_, &As[nb][i * 32 + wv * 8][0]);
        glds16(bgb + (size_t)(i * 32) * K + ko_, &Bs[nb][i * 32 + wv * 8][0]);
      }
    }
#pragma unroll
    for (int kk = 0; kk < 64; kk += 32) {
      bf16x8 af[4], bfr[4];
#pragma unroll
      for (int m = 0; m < 4; ++m) {
        int arw = wr * 64 + m * 16 + lr;
        af[m] = *(const bf16x8*)&As[cur][arw][sw8(arw, kk + lg * 8)];
      }
#pragma unroll
      for (int n = 0; n < 4; ++n) {
        int brw = wc * 64 + n * 16 + lr;
        bfr[n] = *(const bf16x8*)&Bs[cur][brw][sw8(brw, kk + lg * 8)];
      }
#pragma unroll
      for (int m = 0; m < 4; ++m)
#pragma unroll
        for (int n = 0; n < 4; ++n)
          acc[m][n] = __builtin_amdgcn_mfma_f32_16x16x32_bf16(af[m], bfr[n], acc[m][n], 0, 0, 0);
    }
  }

#pragma unroll
  for (int n = 0; n < 4; ++n) {
    int C_ = n0 + wc * 64 + n * 16 + lr;
    float bv = bias[C_];
#pragma unroll
    for (int m = 0; m < 4; ++m) {
#pragma unroll
      for (int r = 0; r < 4; ++r) {
        int R_ = m0 + wr * 64 + m * 16 + lg * 4 + r;
        float v = acc[m][n][r] + bv;
        int which = C_ >> 9, f = C_ & 511, h = f >> 6, d = f & 63;
        int b_ = R_ >> 11, s_ = R_ & 2047;
        if (which == 0) {
          qo[(((size_t)b_ * NH + h) * SQ + s_) * DHD + d] = f2bf(v * QSCALE);
        } else if (which == 1) {
          ko[(((size_t)b_ * NH + h) * SQ + s_) * DHD + d] = f2bf(v);
        } else {
          vo[(((size_t)b_ * NH + h) * DHD + d) * SQ + s_] = f2bf(v);  // V^T [b,h,d,s]
        }
      }
    }
  }
}

// ---------------- Flash attention: QBLK=128, 8-wave blocks, shared K/V stream ----------------
// Block handles one 128-row q-tile (wave w owns rows qb+w*16..+15); all 8 waves share
// the staged K/V tile (1 K-glds + 1 V-glds per wave per tile). Interleaved heavy/light
// dispatch: j = (bx&1) ? bx/2 : 15-bx/2 pairs heavy+light on each CU.
__global__ __launch_bounds__(512) void flash_kernel(
    const unsigned short* __restrict__ Q, const unsigned short* __restrict__ Kb,
    const unsigned short* __restrict__ Vt, unsigned short* __restrict__ ctx,
    float* __restrict__ mstat, float* __restrict__ lstat) {
  __shared__ unsigned short Ks[2][64][64];  // [buf][kpos][dh], swizzled (pre-swz source)
  __shared__ unsigned short Vs[2][64][64];  // [buf][dh][kpos], swizzled
  __shared__ unsigned short Ps[8][16][64];  // per-wave P [q][kpos], swizzled
  int bx = blockIdx.x, h = blockIdx.y, b = blockIdx.z;
  int i2 = bx >> 1;
  int j = (bx & 1) ? i2 : (15 - i2);
  int qb = j * 128;
  int t = threadIdx.x, wv = t >> 6, ln = t & 63, lg = ln >> 4, lr = ln & 15;
  int rsub = ln >> 3;
  int csw = ((ln & 7) ^ rsub) * 8;
  int qrow0 = qb + wv * 16;
  size_t headoff = ((size_t)b * NH + h) * SQ;
  // wave wv stages K rows [wv*8, wv*8+8) and V d-rows [wv*8, wv*8+8)
  const unsigned short* kg = Kb + (headoff + wv * 8 + rsub) * DHD + csw;
  const unsigned short* vg = Vt + (((size_t)b * NH + h) * DHD + wv * 8 + rsub) * SQ + csw;

  const unsigned short* qrow = Q + (headoff + qrow0 + lr) * DHD;
  bf16x8 aq0 = *(const bf16x8*)(qrow + lg * 8);
  bf16x8 aq1 = *(const bf16x8*)(qrow + 32 + lg * 8);

  // ones B-fragment: accumulator col 0 = row-sum of P
  bf16x8 vones;
#pragma unroll
  for (int jj = 0; jj < 8; ++jj) vones[jj] = (lr == 0) ? (short)0x3F80 : (short)0;

  f32x4 cacc[4], lacc;
#pragma unroll
  for (int nd = 0; nd < 4; ++nd)
#pragma unroll
    for (int r = 0; r < 4; ++r) cacc[nd][r] = 0.f;
#pragma unroll
  for (int r = 0; r < 4; ++r) lacc[r] = 0.f;
  float mrun[4];
#pragma unroll
  for (int r = 0; r < 4; ++r) mrun[r] = -__builtin_inff();

  int nkt = (qb >> 6) + 2;  // k-tiles covering rows qb..qb+127
  // prologue: issue tile 0 into buf0
  glds16(kg, &Ks[0][wv * 8][0]);
  glds16(vg, &Vs[0][wv * 8][0]);

  for (int kt = 0; kt < nkt; ++kt) {
    int cur = kt & 1;
    __syncthreads();  // drains glds -> buf[cur] ready
    if (kt + 1 < nkt) {  // issue next tile; latency hides under this iter's compute
      int nb = cur ^ 1;
      size_t ko_ = (size_t)(kt + 1) * 64;
      glds16(kg + ko_ * DHD, &Ks[nb][wv * 8][0]);
      glds16(vg + ko_, &Vs[nb][wv * 8][0]);
    }

    // QK^T (Q pre-scaled; scores in log2 units)
    float sv[4][4];
    __builtin_amdgcn_s_setprio(1);
#pragma unroll
    for (int nt = 0; nt < 4; ++nt) {
      f32x4 sf;
#pragma unroll
      for (int r = 0; r < 4; ++r) sf[r] = 0.f;
      int brw = nt * 16 + lr;
      bf16x8 bk0 = *(const bf16x8*)&Ks[cur][brw][sw8(brw, lg * 8)];
      bf16x8 bk1 = *(const bf16x8*)&Ks[cur][brw][sw8(brw, 32 + lg * 8)];
      sf = __builtin_amdgcn_mfma_f32_16x16x32_bf16(aq0, bk0, sf, 0, 0, 0);
      sf = __builtin_amdgcn_mfma_f32_16x16x32_bf16(aq1, bk1, sf, 0, 0, 0);
#pragma unroll
      for (int r = 0; r < 4; ++r) sv[nt][r] = sf[r];
    }
    __builtin_amdgcn_s_setprio(0);
    if (kt * 64 + 63 > qrow0) {  // tiles at/after this wave's diagonal: causal mask
      int kbase = kt * 64;
#pragma unroll
      for (int nt = 0; nt < 4; ++nt) {
        int kcol = kbase + nt * 16 + lr;
#pragma unroll
        for (int r = 0; r < 4; ++r) {
          int qr = qrow0 + lg * 4 + r;
          if (kcol > qr) sv[nt][r] = -__builtin_inff();
        }
      }
    }

    // online softmax: lane-local defer-max gate (full reduce only when bound exceeded)
    float lmax[4];
    bool need = false;
#pragma unroll
    for (int r = 0; r < 4; ++r) {
      lmax[r] = fmaxf(fmaxf(sv[0][r], sv[1][r]), fmaxf(sv[2][r], sv[3][r]));
      need |= (lmax[r] > mrun[r] + 8.f);
    }
    if (__any(need)) {
#pragma unroll
      for (int r = 0; r < 4; ++r) {
        float tm = lmax[r];
#pragma unroll
        for (int m = 1; m < 16; m <<= 1) tm = fmaxf(tm, __shfl_xor(tm, m));
        float mn = fmaxf(mrun[r], tm);
        float sc = exp2f(mrun[r] - mn);  // -inf -> 0 on first tile
        mrun[r] = mn;
        lacc[r] *= sc;
#pragma unroll
        for (int nd = 0; nd < 4; ++nd) cacc[nd][r] *= sc;
      }
    }
#pragma unroll
    for (int r = 0; r < 4; ++r) {
      int prow = lg * 4 + r;
#pragma unroll
      for (int nt = 0; nt < 4; ++nt) {
        float p = exp2f(sv[nt][r] - mrun[r]);
        Ps[wv][prow][sw8(prow, nt * 16 + lr)] = f2bf(p);
      }
    }

    // PV: A = P, B rows = V^T d-rows (+ ones col for l); per-wave LDS, lgkmcnt orders
    bf16x8 pf0 = *(const bf16x8*)&Ps[wv][lr][sw8(lr, lg * 8)];
    bf16x8 pf1 = *(const bf16x8*)&Ps[wv][lr][sw8(lr, 32 + lg * 8)];
    __builtin_amdgcn_s_setprio(1);
    lacc = __builtin_amdgcn_mfma_f32_16x16x32_bf16(pf0, vones, lacc, 0, 0, 0);
    lacc = __builtin_amdgcn_mfma_f32_16x16x32_bf16(pf1, vones, lacc, 0, 0, 0);
#pragma unroll
    for (int nd = 0; nd < 4; ++nd) {
      int vrw = nd * 16 + lr;
      bf16x8 vf0 = *(const bf16x8*)&Vs[cur][vrw][sw8(vrw, lg * 8)];
      bf16x8 vf1 = *(const bf16x8*)&Vs[cur][vrw][sw8(vrw, 32 + lg * 8)];
      cacc[nd] = __builtin_amdgcn_mfma_f32_16x16x32_bf16(pf0, vf0, cacc[nd], 0, 0, 0);
      cacc[nd] = __builtin_amdgcn_mfma_f32_16x16x32_bf16(pf1, vf1, cacc[nd], 0, 0, 0);
    }
    __builtin_amdgcn_s_setprio(0);
  }

  // epilogue: l lives in lanes lr==0; broadcast within each 16-lane group
  float inv[4];
#pragma unroll
  for (int r = 0; r < 4; ++r) inv[r] = 1.f / __shfl(lacc[r], ln & 48);
#pragma unroll
  for (int nd = 0; nd < 4; ++nd)
#pragma unroll
    for (int r = 0; r < 4; ++r) {
      size_t dst = ((size_t)b * SQ + qrow0 + lg * 4 + r) * EM + h * DHD + nd * 16 + lr;
      ctx[dst] = f2bf(cacc[nd][r] * inv[r]);
    }
  if (lr == 0) {
#pragma unroll
    for (int r = 0; r < 4; ++r) {
      int row = qrow0 + lg * 4 + r;
      mstat[headoff + row] = mrun[r];            // log2 units
      lstat[headoff + row] = 0.125f * inv[r];    // 1/(H*l): attnw uses directly
    }
  }
}

// ---------------- attn_weights: K dbuf (glds) over heads + Q/m/l register pipeline ----------------
__global__ __launch_bounds__(256) void attnw_kernel(
    const unsigned short* __restrict__ Q, const unsigned short* __restrict__ Kb,
    const float* __restrict__ mstat, const float* __restrict__ lstat,
    float* __restrict__ aw) {
  int kt = blockIdx.x, qt = blockIdx.y, b = blockIdx.z;
  int qb = qt * 64, kb = kt * 64;
  int t = threadIdx.x;
  float* tile = aw + ((size_t)b * SQ + qb) * SQ + kb;
  if (kt > qt) {
    int row = t >> 2, c = (t & 3) * 16;
    f32x4 z;
#pragma unroll
    for (int j = 0; j < 4; ++j) z[j] = 0.f;
    float* p = tile + (size_t)row * SQ + c;
    *(f32x4*)p = z; *(f32x4*)(p + 4) = z; *(f32x4*)(p + 8) = z; *(f32x4*)(p + 12) = z;
    return;
  }
  __shared__ unsigned short Ks[2][64][64];
  int wv = t >> 6, ln = t & 63, lg = ln >> 4, lr = ln & 15;
  int rsub = ln >> 3;
  int csw = ((ln & 7) ^ rsub) * 8;
  bool diag = (kt == qt);
  size_t khstride = (size_t)SQ * DHD;
  const unsigned short* kg0 = Kb + (((size_t)b * NH) * SQ + kb + wv * 16 + rsub) * DHD + csw;
  const unsigned short* kg1 = Kb + (((size_t)b * NH) * SQ + kb + wv * 16 + 8 + rsub) * DHD + csw;
  const unsigned short* qg = Q + (((size_t)b * NH) * SQ + qb + wv * 16 + lr) * DHD + lg * 8;
  size_t mbase = (size_t)b * NH * SQ + qb + wv * 16 + lg * 4;

  glds16(kg0, &Ks[0][wv * 16][0]);
  glds16(kg1, &Ks[0][wv * 16 + 8][0]);

  bf16x8 aqc0 = *(const bf16x8*)qg;
  bf16x8 aqc1 = *(const bf16x8*)(qg + 32);
  bf16x8 aqn0 = *(const bf16x8*)(qg + khstride);
  bf16x8 aqn1 = *(const bf16x8*)(qg + khstride + 32);
  float mmc[4], lic[4], mmn[4], lin[4];
#pragma unroll
  for (int r = 0; r < 4; ++r) {
    mmc[r] = mstat[mbase + r];
    lic[r] = lstat[mbase + r];
    mmn[r] = mstat[mbase + SQ + r];
    lin[r] = lstat[mbase + SQ + r];
  }

  f32x4 facc[4];
#pragma unroll
  for (int nt = 0; nt < 4; ++nt)
#pragma unroll
    for (int r = 0; r < 4; ++r) facc[nt][r] = 0.f;

  for (int h = 0; h < NH; ++h) {
    int cur = h & 1;
    __syncthreads();
    if (h + 1 < NH) {
      glds16(kg0 + (size_t)(h + 1) * khstride, &Ks[cur ^ 1][wv * 16][0]);
      glds16(kg1 + (size_t)(h + 1) * khstride, &Ks[cur ^ 1][wv * 16 + 8][0]);
    }

#pragma unroll
    for (int nt = 0; nt < 4; ++nt) {
      f32x4 sf;
#pragma unroll
      for (int r = 0; r < 4; ++r) sf[r] = 0.f;
      int brw = nt * 16 + lr;
      bf16x8 bk0 = *(const bf16x8*)&Ks[cur][brw][sw8(brw, lg * 8)];
      bf16x8 bk1 = *(const bf16x8*)&Ks[cur][brw][sw8(brw, 32 + lg * 8)];
      sf = __builtin_amdgcn_mfma_f32_16x16x32_bf16(aqc0, bk0, sf, 0, 0, 0);
      sf = __builtin_amdgcn_mfma_f32_16x16x32_bf16(aqc1, bk1, sf, 0, 0, 0);
#pragma unroll
      for (int r = 0; r < 4; ++r) facc[nt][r] += exp2f(sf[r] - mmc[r]) * lic[r];
    }

    aqc0 = aqn0; aqc1 = aqn1;
#pragma unroll
    for (int r = 0; r < 4; ++r) { mmc[r] = mmn[r]; lic[r] = lin[r]; }
    if (h + 2 < NH) {
      aqn0 = *(const bf16x8*)(qg + (size_t)(h + 2) * khstride);
      aqn1 = *(const bf16x8*)(qg + (size_t)(h + 2) * khstride + 32);
#pragma unroll
      for (int r = 0; r < 4; ++r) {
        mmn[r] = mstat[mbase + (size_t)(h + 2) * SQ + r];
        lin[r] = lstat[mbase + (size_t)(h + 2) * SQ + r];
      }
    }
  }

#pragma unroll
  for (int nt = 0; nt < 4; ++nt) {
    int kc = kb + nt * 16 + lr;
#pragma unroll
    for (int r = 0; r < 4; ++r) {
      int qr = qb + wv * 16 + lg * 4 + r;
      float v = (diag && kc > qr) ? 0.f : facc[nt][r];
      tile[(size_t)(wv * 16 + lg * 4 + r) * SQ + nt * 16 + lr] = v;
    }
  }
}

extern "C" void kernel_launch(void* const* d_in, const int* in_sizes, int n_in,
                              void* d_out, int out_size, void* d_ws, size_t ws_size,
                              hipStream_t stream) {
  (void)in_sizes; (void)n_in; (void)out_size; (void)ws_size;
  const float* x = (const float*)d_in[0];
  const float* ln1g = (const float*)d_in[1];
  const float* ln1b = (const float*)d_in[2];
  const float* wqkv = (const float*)d_in[3];
  const float* bqkv = (const float*)d_in[4];
  const float* wout = (const float*)d_in[5];
  const float* bout = (const float*)d_in[6];
  const float* ln2g = (const float*)d_in[7];
  const float* ln2b = (const float*)d_in[8];
  const float* wfc1 = (const float*)d_in[9];
  const float* bfc1 = (const float*)d_in[10];
  const float* wfc2 = (const float*)d_in[11];
  const float* bfc2 = (const float*)d_in[12];

  char* ws = (char*)d_ws;
  unsigned short* zctx = (unsigned short*)(ws);               // z (bf16), later reused as ctx
  unsigned short* qb_ = (unsigned short*)(ws + 8388608);      // later reused as LN2 out
  unsigned short* kb_ = (unsigned short*)(ws + 16777216);     // later reused as fc1 out
  unsigned short* vb_ = (unsigned short*)(ws + 25165824);     // V^T [b,h,d,s]
  float* z2 = (float*)(ws + 33554432);                        // fp32 residual stream
  float* mstat = (float*)(ws + 50331648);
  float* lstat = (float*)(ws + 50593792);
  unsigned short* wqkv_h = (unsigned short*)(ws + 50855936);
  unsigned short* wout_h = (unsigned short*)(ws + 52428800);
  unsigned short* wfc1_h = (unsigned short*)(ws + 52953088);
  unsigned short* wfc2_h = (unsigned short*)(ws + 53477376);
  unsigned short* y1 = qb_;
  unsigned short* h1 = kb_;

  float* outy = (float*)d_out;
  float* outw = outy + (size_t)NB * SQ * EM;

  f2bf4_kernel<<<768, 256, 0, stream>>>(wqkv, wout, wfc1, wfc2,
                                        wqkv_h, wout_h, wfc1_h, wfc2_h);

  ln_kernel<<<2048, 256, 0, stream>>>(x, ln1g, ln1b, zctx);
  gemm128<true><<<dim3(64, 12), 256, 0, stream>>>(
      zctx, wqkv_h, bqkv, qb_, kb_, vb_, 8192, 1536, 512);
  flash_kernel<<<dim3(16, 8, 4), 512, 0, stream>>>(qb_, kb_, vb_, zctx, mstat, lstat);
  attnw_kernel<<<dim3(32, 32, 4), 256, 0, stream>>>(qb_, kb_, mstat, lstat, outw);
  gemm64<false, true, true, false><<<dim3(128, 8), 256, 0, stream>>>(
      zctx, wout_h, bout, x, z2, nullptr, nullptr, nullptr, nullptr, 8192, 512, 512);
  ln_kernel<<<2048, 256, 0, stream>>>(z2, ln2g, ln2b, y1);
  gemm64<true, false, false, false><<<dim3(128, 8), 256, 0, stream>>>(
      y1, wfc1_h, bfc1, nullptr, nullptr, h1, nullptr, nullptr, nullptr, 8192, 512, 512);
  gemm64<false, true, true, false><<<dim3(128, 8), 256, 0, stream>>>(
      h1, wfc2_h, bfc2, z2, outy, nullptr, nullptr, nullptr, nullptr, 8192, 512, 512);
}

// Round 16
// 198.720 us; speedup vs baseline: 1.0563x; 1.0563x over previous
//
#include <hip/hip_runtime.h>

typedef short bf16x8 __attribute__((ext_vector_type(8)));
typedef float f32x4 __attribute__((ext_vector_type(4)));
typedef unsigned short u16x8 __attribute__((ext_vector_type(8)));

#define NB 4
#define SQ 2048
#define EM 512
#define NH 8
#define DHD 64
// 1/sqrt(DH) * log2(e): Q pre-scaled so softmax uses exp2
#define QSCALE 0.1803368801111731f

__device__ __forceinline__ unsigned short f2bf(float x) {
  unsigned u = __float_as_uint(x);
  u += 0x7FFFu + ((u >> 16) & 1u);
  return (unsigned short)(u >> 16);
}

__device__ __forceinline__ int sw8(int row, int col8) { return col8 ^ ((row & 7) << 3); }

// async global->LDS, 16B/lane; LDS dest = wave-uniform base + lane*16 (linear).
// Swizzled storage achieved by pre-swizzling the per-lane GLOBAL source address.
__device__ __forceinline__ void glds16(const void* g, void* l) {
  __builtin_amdgcn_global_load_lds(
      (const __attribute__((address_space(1))) void*)g,
      (__attribute__((address_space(3))) void*)l, 16, 0, 0);
}

// ---------------- fused fp32 -> bf16 convert (all 4 weight tensors) ----------------
__global__ __launch_bounds__(256) void f2bf4_kernel(
    const float* __restrict__ w0, const float* __restrict__ w1,
    const float* __restrict__ w2, const float* __restrict__ w3,
    unsigned short* __restrict__ o0, unsigned short* __restrict__ o1,
    unsigned short* __restrict__ o2, unsigned short* __restrict__ o3) {
  int i = (blockIdx.x * 256 + threadIdx.x) * 8;
  const float* src;
  unsigned short* dst;
  int off;
  if (i < 786432) { src = w0; dst = o0; off = i; }
  else if (i < 1048576) { src = w1; dst = o1; off = i - 786432; }
  else if (i < 1310720) { src = w2; dst = o2; off = i - 1048576; }
  else { src = w3; dst = o3; off = i - 1310720; }
  f32x4 a = *(const f32x4*)(src + off);
  f32x4 b = *(const f32x4*)(src + off + 4);
  u16x8 o;
#pragma unroll
  for (int j = 0; j < 4; ++j) { o[j] = f2bf(a[j]); o[j + 4] = f2bf(b[j]); }
  *(u16x8*)(dst + off) = o;
}

// ---------------- LayerNorm (row = E=512), fp32 in -> bf16 out ----------------
__global__ __launch_bounds__(256) void ln_kernel(const float* __restrict__ x,
                                                 const float* __restrict__ g,
                                                 const float* __restrict__ bb,
                                                 unsigned short* __restrict__ out) {
  int tid = threadIdx.x;
  int row = blockIdx.x * 4 + (tid >> 6);
  int lane = tid & 63;
  size_t base = (size_t)row * EM + lane * 8;
  f32x4 v0 = *(const f32x4*)(x + base);
  f32x4 v1 = *(const f32x4*)(x + base + 4);
  float s = 0.f, q = 0.f;
#pragma unroll
  for (int j = 0; j < 4; ++j) { s += v0[j] + v1[j]; q += v0[j] * v0[j] + v1[j] * v1[j]; }
#pragma unroll
  for (int m = 1; m < 64; m <<= 1) { s += __shfl_xor(s, m); q += __shfl_xor(q, m); }
  float mean = s * (1.f / EM);
  float var = q * (1.f / EM) - mean * mean;
  float rs = rsqrtf(var + 1e-5f);
  f32x4 g0 = *(const f32x4*)(g + lane * 8), g1 = *(const f32x4*)(g + lane * 8 + 4);
  f32x4 b0 = *(const f32x4*)(bb + lane * 8), b1 = *(const f32x4*)(bb + lane * 8 + 4);
  u16x8 o;
#pragma unroll
  for (int j = 0; j < 4; ++j) {
    o[j] = f2bf((v0[j] - mean) * rs * g0[j] + b0[j]);
    o[j + 4] = f2bf((v1[j] - mean) * rs * g1[j] + b1[j]);
  }
  *(u16x8*)(out + base) = o;
}

// ---------------- GEMM 64x64: dbuf LDS via global_load_lds (1 barrier/iter) ----------------
template <bool LEAKY, bool RESID, bool OUTF32, bool QKV>
__global__ __launch_bounds__(256) void gemm64(
    const unsigned short* __restrict__ A, const unsigned short* __restrict__ Bm,
    const float* __restrict__ bias, const float* __restrict__ resid,
    float* __restrict__ outf, unsigned short* __restrict__ outh,
    unsigned short* __restrict__ qo, unsigned short* __restrict__ ko,
    unsigned short* __restrict__ vo, int M, int N, int K) {
  __shared__ unsigned short As[2][64][64];
  __shared__ unsigned short Bs[2][64][64];
  int m0 = blockIdx.x * 64, n0 = blockIdx.y * 64;
  int t = threadIdx.x;
  int wv = t >> 6, ln = t & 63, lg = ln >> 4, lr = ln & 15;
  int rsub = ln >> 3;
  int csw = ((ln & 7) ^ rsub) * 8;
  f32x4 acc[4];
#pragma unroll
  for (int c = 0; c < 4; ++c)
#pragma unroll
    for (int r = 0; r < 4; ++r) acc[c][r] = 0.f;

  const unsigned short* ag0 = A + (size_t)(m0 + wv * 16 + rsub) * K + csw;
  const unsigned short* ag1 = A + (size_t)(m0 + wv * 16 + 8 + rsub) * K + csw;
  const unsigned short* bg0 = Bm + (size_t)(n0 + wv * 16 + rsub) * K + csw;
  const unsigned short* bg1 = Bm + (size_t)(n0 + wv * 16 + 8 + rsub) * K + csw;

  glds16(ag0, &As[0][wv * 16][0]);
  glds16(ag1, &As[0][wv * 16 + 8][0]);
  glds16(bg0, &Bs[0][wv * 16][0]);
  glds16(bg1, &Bs[0][wv * 16 + 8][0]);

  int nk = K >> 6;
  for (int ki = 0; ki < nk; ++ki) {
    int cur = ki & 1;
    __syncthreads();
    if (ki + 1 < nk) {
      int nb = cur ^ 1;
      int ko_ = (ki + 1) * 64;
      glds16(ag0 + ko_, &As[nb][wv * 16][0]);
      glds16(ag1 + ko_, &As[nb][wv * 16 + 8][0]);
      glds16(bg0 + ko_, &Bs[nb][wv * 16][0]);
      glds16(bg1 + ko_, &Bs[nb][wv * 16 + 8][0]);
    }
#pragma unroll
    for (int kk = 0; kk < 64; kk += 32) {
      int arw = wv * 16 + lr;
      bf16x8 af = *(const bf16x8*)&As[cur][arw][sw8(arw, kk + lg * 8)];
#pragma unroll
      for (int c = 0; c < 4; ++c) {
        int brw = c * 16 + lr;
        bf16x8 bf = *(const bf16x8*)&Bs[cur][brw][sw8(brw, kk + lg * 8)];
        acc[c] = __builtin_amdgcn_mfma_f32_16x16x32_bf16(af, bf, acc[c], 0, 0, 0);
      }
    }
  }
#pragma unroll
  for (int c = 0; c < 4; ++c) {
    int C_ = n0 + c * 16 + lr;
    float bv = bias[C_];
#pragma unroll
    for (int r = 0; r < 4; ++r) {
      int R_ = m0 + wv * 16 + lg * 4 + r;
      float v = acc[c][r] + bv;
      if (LEAKY) v = v > 0.f ? v : 0.01f * v;
      if (RESID) v += resid[(size_t)R_ * N + C_];
      if (QKV) {
        int which = C_ >> 9, f = C_ & 511, h = f >> 6, d = f & 63;
        int b_ = R_ >> 11, s_ = R_ & 2047;
        if (which == 0) {
          qo[(((size_t)b_ * NH + h) * SQ + s_) * DHD + d] = f2bf(v * QSCALE);
        } else if (which == 1) {
          ko[(((size_t)b_ * NH + h) * SQ + s_) * DHD + d] = f2bf(v);
        } else {
          vo[(((size_t)b_ * NH + h) * DHD + d) * SQ + s_] = f2bf(v);  // V^T [b,h,d,s]
        }
      } else if (OUTF32) {
        outf[(size_t)R_ * N + C_] = v;
      } else {
        outh[(size_t)R_ * N + C_] = f2bf(v);
      }
    }
  }
}

// ---------------- GEMM 128x128 (QKV only): dbuf LDS via glds, 2x2 wave quadrants ----------------
template <bool QKV>
__global__ __launch_bounds__(256) void gemm128(
    const unsigned short* __restrict__ A, const unsigned short* __restrict__ Bm,
    const float* __restrict__ bias, unsigned short* __restrict__ qo,
    unsigned short* __restrict__ ko, unsigned short* __restrict__ vo,
    int M, int N, int K) {
  __shared__ unsigned short As[2][128][64];
  __shared__ unsigned short Bs[2][128][64];
  int m0 = blockIdx.x * 128, n0 = blockIdx.y * 128;
  int t = threadIdx.x;
  int wv = t >> 6, ln = t & 63, lg = ln >> 4, lr = ln & 15;
  int wr = wv >> 1, wc = wv & 1;
  int rsub = ln >> 3;
  int csw = ((ln & 7) ^ rsub) * 8;
  f32x4 acc[4][4];
#pragma unroll
  for (int m = 0; m < 4; ++m)
#pragma unroll
    for (int n = 0; n < 4; ++n)
#pragma unroll
      for (int r = 0; r < 4; ++r) acc[m][n][r] = 0.f;

  const unsigned short* agb = A + (size_t)(m0 + wv * 8 + rsub) * K + csw;
  const unsigned short* bgb = Bm + (size_t)(n0 + wv * 8 + rsub) * K + csw;

#pragma unroll
  for (int i = 0; i < 4; ++i) {
    glds16(agb + (size_t)(i * 32) * K, &As[0][i * 32 + wv * 8][0]);
    glds16(bgb + (size_t)(i * 32) * K, &Bs[0][i * 32 + wv * 8][0]);
  }

  int nk = K >> 6;
  for (int ki = 0; ki < nk; ++ki) {
    int cur = ki & 1;
    __syncthreads();
    if (ki + 1 < nk) {
      int nb = cur ^ 1;
      int ko_ = (ki + 1) * 64;
#pragma unroll
      for (int i = 0; i < 4; ++i) {
        glds16(agb + (size_t)(i * 32) * K + ko_, &As[nb][i * 32 + wv * 8][0]);
        glds16(bgb + (size_t)(i * 32) * K + ko_, &Bs[nb][i * 32 + wv * 8][0]);
      }
    }
#pragma unroll
    for (int kk = 0; kk < 64; kk += 32) {
      bf16x8 af[4], bfr[4];
#pragma unroll
      for (int m = 0; m < 4; ++m) {
        int arw = wr * 64 + m * 16 + lr;
        af[m] = *(const bf16x8*)&As[cur][arw][sw8(arw, kk + lg * 8)];
      }
#pragma unroll
      for (int n = 0; n < 4; ++n) {
        int brw = wc * 64 + n * 16 + lr;
        bfr[n] = *(const bf16x8*)&Bs[cur][brw][sw8(brw, kk + lg * 8)];
      }
#pragma unroll
      for (int m = 0; m < 4; ++m)
#pragma unroll
        for (int n = 0; n < 4; ++n)
          acc[m][n] = __builtin_amdgcn_mfma_f32_16x16x32_bf16(af[m], bfr[n], acc[m][n], 0, 0, 0);
    }
  }

#pragma unroll
  for (int n = 0; n < 4; ++n) {
    int C_ = n0 + wc * 64 + n * 16 + lr;
    float bv = bias[C_];
#pragma unroll
    for (int m = 0; m < 4; ++m) {
#pragma unroll
      for (int r = 0; r < 4; ++r) {
        int R_ = m0 + wr * 64 + m * 16 + lg * 4 + r;
        float v = acc[m][n][r] + bv;
        int which = C_ >> 9, f = C_ & 511, h = f >> 6, d = f & 63;
        int b_ = R_ >> 11, s_ = R_ & 2047;
        if (which == 0) {
          qo[(((size_t)b_ * NH + h) * SQ + s_) * DHD + d] = f2bf(v * QSCALE);
        } else if (which == 1) {
          ko[(((size_t)b_ * NH + h) * SQ + s_) * DHD + d] = f2bf(v);
        } else {
          vo[(((size_t)b_ * NH + h) * DHD + d) * SQ + s_] = f2bf(v);  // V^T [b,h,d,s]
        }
      }
    }
  }
}

// ---------------- Flash attention: paired q-tiles {31-bx heavy, bx light}, dbuf + glds ----------------
__global__ __launch_bounds__(256) void flash_kernel(
    const unsigned short* __restrict__ Q, const unsigned short* __restrict__ Kb,
    const unsigned short* __restrict__ Vt, unsigned short* __restrict__ ctx,
    float* __restrict__ mstat, float* __restrict__ lstat) {
  __shared__ unsigned short Ks[2][64][64];  // [buf][kpos][dh], swizzled (pre-swz source)
  __shared__ unsigned short Vs[2][64][64];  // [buf][dh][kpos], swizzled
  __shared__ unsigned short Ps[4][16][64];  // per-wave P [q][kpos], swizzled
  int h = blockIdx.y, b = blockIdx.z;
  int t = threadIdx.x, wv = t >> 6, ln = t & 63, lg = ln >> 4, lr = ln & 15;
  int rsub = ln >> 3;
  int csw = ((ln & 7) ^ rsub) * 8;
  size_t headoff = ((size_t)b * NH + h) * SQ;
  const unsigned short* kg0 = Kb + (headoff + wv * 16 + rsub) * DHD + csw;
  const unsigned short* kg1 = Kb + (headoff + wv * 16 + 8 + rsub) * DHD + csw;
  const unsigned short* vg0 = Vt + (((size_t)b * NH + h) * DHD + wv * 16 + rsub) * SQ + csw;
  const unsigned short* vg1 = Vt + (((size_t)b * NH + h) * DHD + wv * 16 + 8 + rsub) * SQ + csw;

  // ones B-fragment: accumulator col 0 = row-sum of P
  bf16x8 vones;
#pragma unroll
  for (int j = 0; j < 8; ++j) vones[j] = (lr == 0) ? (short)0x3F80 : (short)0;

  for (int half = 0; half < 2; ++half) {
    int qt = half ? blockIdx.x : (31 - blockIdx.x);  // heavy half first
    int qb = qt * 64;
    const unsigned short* qrow = Q + (headoff + qb + wv * 16 + lr) * DHD;
    bf16x8 aq0 = *(const bf16x8*)(qrow + lg * 8);
    bf16x8 aq1 = *(const bf16x8*)(qrow + 32 + lg * 8);

    f32x4 cacc[4], lacc;
#pragma unroll
    for (int nd = 0; nd < 4; ++nd)
#pragma unroll
      for (int r = 0; r < 4; ++r) cacc[nd][r] = 0.f;
#pragma unroll
    for (int r = 0; r < 4; ++r) lacc[r] = 0.f;
    float mrun[4];
#pragma unroll
    for (int r = 0; r < 4; ++r) mrun[r] = -__builtin_inff();

    int nkt = qt + 1;
    __syncthreads();  // previous half's LDS reads fully done
    glds16(kg0, &Ks[0][wv * 16][0]);
    glds16(kg1, &Ks[0][wv * 16 + 8][0]);
    glds16(vg0, &Vs[0][wv * 16][0]);
    glds16(vg1, &Vs[0][wv * 16 + 8][0]);

    for (int kt = 0; kt < nkt; ++kt) {
      int cur = kt & 1;
      __syncthreads();  // drains glds -> buf[cur] ready
      if (kt + 1 < nkt) {
        int nb = cur ^ 1;
        size_t ko_ = (size_t)(kt + 1) * 64;
        glds16(kg0 + ko_ * DHD, &Ks[nb][wv * 16][0]);
        glds16(kg1 + ko_ * DHD, &Ks[nb][wv * 16 + 8][0]);
        glds16(vg0 + ko_, &Vs[nb][wv * 16][0]);
        glds16(vg1 + ko_, &Vs[nb][wv * 16 + 8][0]);
      }

      // QK^T (Q pre-scaled; scores in log2 units)
      float sv[4][4];
      __builtin_amdgcn_s_setprio(1);
#pragma unroll
      for (int nt = 0; nt < 4; ++nt) {
        f32x4 sf;
#pragma unroll
        for (int r = 0; r < 4; ++r) sf[r] = 0.f;
        int brw = nt * 16 + lr;
        bf16x8 bk0 = *(const bf16x8*)&Ks[cur][brw][sw8(brw, lg * 8)];
        bf16x8 bk1 = *(const bf16x8*)&Ks[cur][brw][sw8(brw, 32 + lg * 8)];
        sf = __builtin_amdgcn_mfma_f32_16x16x32_bf16(aq0, bk0, sf, 0, 0, 0);
        sf = __builtin_amdgcn_mfma_f32_16x16x32_bf16(aq1, bk1, sf, 0, 0, 0);
#pragma unroll
        for (int r = 0; r < 4; ++r) sv[nt][r] = sf[r];
      }
      __builtin_amdgcn_s_setprio(0);
      if (kt == nkt - 1) {
        int kbase = kt * 64;
#pragma unroll
        for (int nt = 0; nt < 4; ++nt) {
          int kcol = kbase + nt * 16 + lr;
#pragma unroll
          for (int r = 0; r < 4; ++r) {
            int qr = qb + wv * 16 + lg * 4 + r;
            if (kcol > qr) sv[nt][r] = -__builtin_inff();
          }
        }
      }

      // online softmax: lane-local defer-max gate
      float lmax[4];
      bool need = false;
#pragma unroll
      for (int r = 0; r < 4; ++r) {
        lmax[r] = fmaxf(fmaxf(sv[0][r], sv[1][r]), fmaxf(sv[2][r], sv[3][r]));
        need |= (lmax[r] > mrun[r] + 8.f);
      }
      if (__any(need)) {
#pragma unroll
        for (int r = 0; r < 4; ++r) {
          float tm = lmax[r];
#pragma unroll
          for (int m = 1; m < 16; m <<= 1) tm = fmaxf(tm, __shfl_xor(tm, m));
          float mn = fmaxf(mrun[r], tm);
          float sc = exp2f(mrun[r] - mn);
          mrun[r] = mn;
          lacc[r] *= sc;
#pragma unroll
          for (int nd = 0; nd < 4; ++nd) cacc[nd][r] *= sc;
        }
      }
      // P-store: truncating f32->bf16 (1 op); downward bias cancels via l (ones-MFMA
      // sums the SAME truncated values), so O = sum(P V)/sum(P) is unbiased to 1st order.
#pragma unroll
      for (int r = 0; r < 4; ++r) {
        int prow = lg * 4 + r;
#pragma unroll
        for (int nt = 0; nt < 4; ++nt) {
          float p = exp2f(sv[nt][r] - mrun[r]);
          Ps[wv][prow][sw8(prow, nt * 16 + lr)] =
              (unsigned short)(__float_as_uint(p) >> 16);
        }
      }

      // PV
      bf16x8 pf0 = *(const bf16x8*)&Ps[wv][lr][sw8(lr, lg * 8)];
      bf16x8 pf1 = *(const bf16x8*)&Ps[wv][lr][sw8(lr, 32 + lg * 8)];
      __builtin_amdgcn_s_setprio(1);
      lacc = __builtin_amdgcn_mfma_f32_16x16x32_bf16(pf0, vones, lacc, 0, 0, 0);
      lacc = __builtin_amdgcn_mfma_f32_16x16x32_bf16(pf1, vones, lacc, 0, 0, 0);
#pragma unroll
      for (int nd = 0; nd < 4; ++nd) {
        int vrw = nd * 16 + lr;
        bf16x8 vf0 = *(const bf16x8*)&Vs[cur][vrw][sw8(vrw, lg * 8)];
        bf16x8 vf1 = *(const bf16x8*)&Vs[cur][vrw][sw8(vrw, 32 + lg * 8)];
        cacc[nd] = __builtin_amdgcn_mfma_f32_16x16x32_bf16(pf0, vf0, cacc[nd], 0, 0, 0);
        cacc[nd] = __builtin_amdgcn_mfma_f32_16x16x32_bf16(pf1, vf1, cacc[nd], 0, 0, 0);
      }
      __builtin_amdgcn_s_setprio(0);
    }

    float inv[4];
#pragma unroll
    for (int r = 0; r < 4; ++r) inv[r] = 1.f / __shfl(lacc[r], ln & 48);
#pragma unroll
    for (int nd = 0; nd < 4; ++nd)
#pragma unroll
      for (int r = 0; r < 4; ++r) {
        size_t dst = ((size_t)b * SQ + qb + wv * 16 + lg * 4 + r) * EM + h * DHD + nd * 16 + lr;
        ctx[dst] = f2bf(cacc[nd][r] * inv[r]);
      }
    if (lr == 0) {
#pragma unroll
      for (int r = 0; r < 4; ++r) {
        int row = qb + wv * 16 + lg * 4 + r;
        mstat[headoff + row] = mrun[r];            // log2 units
        lstat[headoff + row] = 0.125f * inv[r];    // 1/(H*l): attnw uses directly
      }
    }
  }
}

// ---------------- attn_weights: 2 heads per barrier (4 K bufs) + Q/m/l register pipeline ----------------
__global__ __launch_bounds__(256) void attnw_kernel(
    const unsigned short* __restrict__ Q, const unsigned short* __restrict__ Kb,
    const float* __restrict__ mstat, const float* __restrict__ lstat,
    float* __restrict__ aw) {
  int kt = blockIdx.x, qt = blockIdx.y, b = blockIdx.z;
  int qb = qt * 64, kb = kt * 64;
  int t = threadIdx.x;
  float* tile = aw + ((size_t)b * SQ + qb) * SQ + kb;
  if (kt > qt) {
    int row = t >> 2, c = (t & 3) * 16;
    f32x4 z;
#pragma unroll
    for (int j = 0; j < 4; ++j) z[j] = 0.f;
    float* p = tile + (size_t)row * SQ + c;
    *(f32x4*)p = z; *(f32x4*)(p + 4) = z; *(f32x4*)(p + 8) = z; *(f32x4*)(p + 12) = z;
    return;
  }
  __shared__ unsigned short Ks[4][64][64];  // 32 KB, heads h..h+3 in flight
  int wv = t >> 6, ln = t & 63, lg = ln >> 4, lr = ln & 15;
  int rsub = ln >> 3;
  int csw = ((ln & 7) ^ rsub) * 8;
  bool diag = (kt == qt);
  size_t khstride = (size_t)SQ * DHD;
  const unsigned short* kg0 = Kb + (((size_t)b * NH) * SQ + kb + wv * 16 + rsub) * DHD + csw;
  const unsigned short* kg1 = Kb + (((size_t)b * NH) * SQ + kb + wv * 16 + 8 + rsub) * DHD + csw;
  const unsigned short* qg = Q + (((size_t)b * NH) * SQ + qb + wv * 16 + lr) * DHD + lg * 8;
  size_t mbase = (size_t)b * NH * SQ + qb + wv * 16 + lg * 4;

  // prologue: issue K for heads 0,1
  glds16(kg0, &Ks[0][wv * 16][0]);
  glds16(kg1, &Ks[0][wv * 16 + 8][0]);
  glds16(kg0 + khstride, &Ks[1][wv * 16][0]);
  glds16(kg1 + khstride, &Ks[1][wv * 16 + 8][0]);

  // Q/m/l register pipeline: pair (A,B) = heads h,h+1; pair (C,D) = heads h+2,h+3
  bf16x8 qA0 = *(const bf16x8*)qg;
  bf16x8 qA1 = *(const bf16x8*)(qg + 32);
  bf16x8 qB0 = *(const bf16x8*)(qg + khstride);
  bf16x8 qB1 = *(const bf16x8*)(qg + khstride + 32);
  bf16x8 qC0 = *(const bf16x8*)(qg + 2 * khstride);
  bf16x8 qC1 = *(const bf16x8*)(qg + 2 * khstride + 32);
  bf16x8 qD0 = *(const bf16x8*)(qg + 3 * khstride);
  bf16x8 qD1 = *(const bf16x8*)(qg + 3 * khstride + 32);
  float mA[4], lA[4], mB[4], lB[4], mC[4], lC[4], mD[4], lD[4];
#pragma unroll
  for (int r = 0; r < 4; ++r) {
    mA[r] = mstat[mbase + r];           lA[r] = lstat[mbase + r];
    mB[r] = mstat[mbase + SQ + r];      lB[r] = lstat[mbase + SQ + r];
    mC[r] = mstat[mbase + 2 * SQ + r];  lC[r] = lstat[mbase + 2 * SQ + r];
    mD[r] = mstat[mbase + 3 * SQ + r];  lD[r] = lstat[mbase + 3 * SQ + r];
  }

  f32x4 facc[4];
#pragma unroll
  for (int nt = 0; nt < 4; ++nt)
#pragma unroll
    for (int r = 0; r < 4; ++r) facc[nt][r] = 0.f;

  for (int h = 0; h < NH; h += 2) {
    __syncthreads();  // drains glds -> bufs h&3,(h+1)&3 ready
    if (h + 2 < NH) {  // issue K for heads h+2,h+3 into the other buffer pair
      glds16(kg0 + (size_t)(h + 2) * khstride, &Ks[(h + 2) & 3][wv * 16][0]);
      glds16(kg1 + (size_t)(h + 2) * khstride, &Ks[(h + 2) & 3][wv * 16 + 8][0]);
      glds16(kg0 + (size_t)(h + 3) * khstride, &Ks[(h + 3) & 3][wv * 16][0]);
      glds16(kg1 + (size_t)(h + 3) * khstride, &Ks[(h + 3) & 3][wv * 16 + 8][0]);
    }

    // two independent head computations -> ILP across MFMA + exp2 chains
#pragma unroll
    for (int nt = 0; nt < 4; ++nt) {
      int brw = nt * 16 + lr;
      f32x4 sfA, sfB;
#pragma unroll
      for (int r = 0; r < 4; ++r) { sfA[r] = 0.f; sfB[r] = 0.f; }
      bf16x8 bkA0 = *(const bf16x8*)&Ks[h & 3][brw][sw8(brw, lg * 8)];
      bf16x8 bkA1 = *(const bf16x8*)&Ks[h & 3][brw][sw8(brw, 32 + lg * 8)];
      bf16x8 bkB0 = *(const bf16x8*)&Ks[(h + 1) & 3][brw][sw8(brw, lg * 8)];
      bf16x8 bkB1 = *(const bf16x8*)&Ks[(h + 1) & 3][brw][sw8(brw, 32 + lg * 8)];
      sfA = __builtin_amdgcn_mfma_f32_16x16x32_bf16(qA0, bkA0, sfA, 0, 0, 0);
      sfB = __builtin_amdgcn_mfma_f32_16x16x32_bf16(qB0, bkB0, sfB, 0, 0, 0);
      sfA = __builtin_amdgcn_mfma_f32_16x16x32_bf16(qA1, bkA1, sfA, 0, 0, 0);
      sfB = __builtin_amdgcn_mfma_f32_16x16x32_bf16(qB1, bkB1, sfB, 0, 0, 0);
#pragma unroll
      for (int r = 0; r < 4; ++r) {
        facc[nt][r] += exp2f(sfA[r] - mA[r]) * lA[r];
        facc[nt][r] += exp2f(sfB[r] - mB[r]) * lB[r];
      }
    }

    // rotate pipeline: (C,D) -> (A,B); prefetch heads h+4,h+5
    qA0 = qC0; qA1 = qC1; qB0 = qD0; qB1 = qD1;
#pragma unroll
    for (int r = 0; r < 4; ++r) {
      mA[r] = mC[r]; lA[r] = lC[r];
      mB[r] = mD[r]; lB[r] = lD[r];
    }
    if (h + 4 < NH) {
      qC0 = *(const bf16x8*)(qg + (size_t)(h + 4) * khstride);
      qC1 = *(const bf16x8*)(qg + (size_t)(h + 4) * khstride + 32);
      qD0 = *(const bf16x8*)(qg + (size_t)(h + 5) * khstride);
      qD1 = *(const bf16x8*)(qg + (size_t)(h + 5) * khstride + 32);
#pragma unroll
      for (int r = 0; r < 4; ++r) {
        mC[r] = mstat[mbase + (size_t)(h + 4) * SQ + r];
        lC[r] = lstat[mbase + (size_t)(h + 4) * SQ + r];
        mD[r] = mstat[mbase + (size_t)(h + 5) * SQ + r];
        lD[r] = lstat[mbase + (size_t)(h + 5) * SQ + r];
      }
    }
  }

  // write; apply causal mask once (diagonal tile only)
#pragma unroll
  for (int nt = 0; nt < 4; ++nt) {
    int kc = kb + nt * 16 + lr;
#pragma unroll
    for (int r = 0; r < 4; ++r) {
      int qr = qb + wv * 16 + lg * 4 + r;
      float v = (diag && kc > qr) ? 0.f : facc[nt][r];
      tile[(size_t)(wv * 16 + lg * 4 + r) * SQ + nt * 16 + lr] = v;
    }
  }
}

extern "C" void kernel_launch(void* const* d_in, const int* in_sizes, int n_in,
                              void* d_out, int out_size, void* d_ws, size_t ws_size,
                              hipStream_t stream) {
  (void)in_sizes; (void)n_in; (void)out_size; (void)ws_size;
  const float* x = (const float*)d_in[0];
  const float* ln1g = (const float*)d_in[1];
  const float* ln1b = (const float*)d_in[2];
  const float* wqkv = (const float*)d_in[3];
  const float* bqkv = (const float*)d_in[4];
  const float* wout = (const float*)d_in[5];
  const float* bout = (const float*)d_in[6];
  const float* ln2g = (const float*)d_in[7];
  const float* ln2b = (const float*)d_in[8];
  const float* wfc1 = (const float*)d_in[9];
  const float* bfc1 = (const float*)d_in[10];
  const float* wfc2 = (const float*)d_in[11];
  const float* bfc2 = (const float*)d_in[12];

  char* ws = (char*)d_ws;
  unsigned short* zctx = (unsigned short*)(ws);               // z (bf16), later reused as ctx
  unsigned short* qb_ = (unsigned short*)(ws + 8388608);      // later reused as LN2 out
  unsigned short* kb_ = (unsigned short*)(ws + 16777216);     // later reused as fc1 out
  unsigned short* vb_ = (unsigned short*)(ws + 25165824);     // V^T [b,h,d,s]
  float* z2 = (float*)(ws + 33554432);                        // fp32 residual stream
  float* mstat = (float*)(ws + 50331648);
  float* lstat = (float*)(ws + 50593792);
  unsigned short* wqkv_h = (unsigned short*)(ws + 50855936);
  unsigned short* wout_h = (unsigned short*)(ws + 52428800);
  unsigned short* wfc1_h = (unsigned short*)(ws + 52953088);
  unsigned short* wfc2_h = (unsigned short*)(ws + 53477376);
  unsigned short* y1 = qb_;
  unsigned short* h1 = kb_;

  float* outy = (float*)d_out;
  float* outw = outy + (size_t)NB * SQ * EM;

  f2bf4_kernel<<<768, 256, 0, stream>>>(wqkv, wout, wfc1, wfc2,
                                        wqkv_h, wout_h, wfc1_h, wfc2_h);

  ln_kernel<<<2048, 256, 0, stream>>>(x, ln1g, ln1b, zctx);
  gemm128<true><<<dim3(64, 12), 256, 0, stream>>>(
      zctx, wqkv_h, bqkv, qb_, kb_, vb_, 8192, 1536, 512);
  flash_kernel<<<dim3(16, 8, 4), 256, 0, stream>>>(qb_, kb_, vb_, zctx, mstat, lstat);
  attnw_kernel<<<dim3(32, 32, 4), 256, 0, stream>>>(qb_, kb_, mstat, lstat, outw);
  gemm64<false, true, true, false><<<dim3(128, 8), 256, 0, stream>>>(
      zctx, wout_h, bout, x, z2, nullptr, nullptr, nullptr, nullptr, 8192, 512, 512);
  ln_kernel<<<2048, 256, 0, stream>>>(z2, ln2g, ln2b, y1);
  gemm64<true, false, false, false><<<dim3(128, 8), 256, 0, stream>>>(
      y1, wfc1_h, bfc1, nullptr, nullptr, h1, nullptr, nullptr, nullptr, 8192, 512, 512);
  gemm64<false, true, true, false><<<dim3(128, 8), 256, 0, stream>>>(
      h1, wfc2_h, bfc2, z2, outy, nullptr, nullptr, nullptr, nullptr, 8192, 512, 512);
}

// Round 17
// 186.232 us; speedup vs baseline: 1.1271x; 1.0671x over previous
//
#include <hip/hip_runtime.h>

typedef short bf16x8 __attribute__((ext_vector_type(8)));
typedef float f32x4 __attribute__((ext_vector_type(4)));
typedef unsigned short u16x8 __attribute__((ext_vector_type(8)));

#define NB 4
#define SQ 2048
#define EM 512
#define NH 8
#define DHD 64
// 1/sqrt(DH) * log2(e): Q pre-scaled so softmax uses exp2
#define QSCALE 0.1803368801111731f

__device__ __forceinline__ unsigned short f2bf(float x) {
  unsigned u = __float_as_uint(x);
  u += 0x7FFFu + ((u >> 16) & 1u);
  return (unsigned short)(u >> 16);
}

__device__ __forceinline__ int sw8(int row, int col8) { return col8 ^ ((row & 7) << 3); }

// async global->LDS, 16B/lane; LDS dest = wave-uniform base + lane*16 (linear).
// Swizzled storage achieved by pre-swizzling the per-lane GLOBAL source address.
__device__ __forceinline__ void glds16(const void* g, void* l) {
  __builtin_amdgcn_global_load_lds(
      (const __attribute__((address_space(1))) void*)g,
      (__attribute__((address_space(3))) void*)l, 16, 0, 0);
}

// ---------------- fused fp32 -> bf16 convert (all 4 weight tensors) ----------------
__global__ __launch_bounds__(256) void f2bf4_kernel(
    const float* __restrict__ w0, const float* __restrict__ w1,
    const float* __restrict__ w2, const float* __restrict__ w3,
    unsigned short* __restrict__ o0, unsigned short* __restrict__ o1,
    unsigned short* __restrict__ o2, unsigned short* __restrict__ o3) {
  int i = (blockIdx.x * 256 + threadIdx.x) * 8;
  const float* src;
  unsigned short* dst;
  int off;
  if (i < 786432) { src = w0; dst = o0; off = i; }
  else if (i < 1048576) { src = w1; dst = o1; off = i - 786432; }
  else if (i < 1310720) { src = w2; dst = o2; off = i - 1048576; }
  else { src = w3; dst = o3; off = i - 1310720; }
  f32x4 a = *(const f32x4*)(src + off);
  f32x4 b = *(const f32x4*)(src + off + 4);
  u16x8 o;
#pragma unroll
  for (int j = 0; j < 4; ++j) { o[j] = f2bf(a[j]); o[j + 4] = f2bf(b[j]); }
  *(u16x8*)(dst + off) = o;
}

// ---------------- LayerNorm (row = E=512), fp32 in -> bf16 out ----------------
__global__ __launch_bounds__(256) void ln_kernel(const float* __restrict__ x,
                                                 const float* __restrict__ g,
                                                 const float* __restrict__ bb,
                                                 unsigned short* __restrict__ out) {
  int tid = threadIdx.x;
  int row = blockIdx.x * 4 + (tid >> 6);
  int lane = tid & 63;
  size_t base = (size_t)row * EM + lane * 8;
  f32x4 v0 = *(const f32x4*)(x + base);
  f32x4 v1 = *(const f32x4*)(x + base + 4);
  float s = 0.f, q = 0.f;
#pragma unroll
  for (int j = 0; j < 4; ++j) { s += v0[j] + v1[j]; q += v0[j] * v0[j] + v1[j] * v1[j]; }
#pragma unroll
  for (int m = 1; m < 64; m <<= 1) { s += __shfl_xor(s, m); q += __shfl_xor(q, m); }
  float mean = s * (1.f / EM);
  float var = q * (1.f / EM) - mean * mean;
  float rs = rsqrtf(var + 1e-5f);
  f32x4 g0 = *(const f32x4*)(g + lane * 8), g1 = *(const f32x4*)(g + lane * 8 + 4);
  f32x4 b0 = *(const f32x4*)(bb + lane * 8), b1 = *(const f32x4*)(bb + lane * 8 + 4);
  u16x8 o;
#pragma unroll
  for (int j = 0; j < 4; ++j) {
    o[j] = f2bf((v0[j] - mean) * rs * g0[j] + b0[j]);
    o[j + 4] = f2bf((v1[j] - mean) * rs * g1[j] + b1[j]);
  }
  *(u16x8*)(out + base) = o;
}

// ---------------- GEMM 64x64: dbuf LDS via global_load_lds (1 barrier/iter) ----------------
template <bool LEAKY, bool RESID, bool OUTF32, bool QKV>
__global__ __launch_bounds__(256) void gemm64(
    const unsigned short* __restrict__ A, const unsigned short* __restrict__ Bm,
    const float* __restrict__ bias, const float* __restrict__ resid,
    float* __restrict__ outf, unsigned short* __restrict__ outh,
    unsigned short* __restrict__ qo, unsigned short* __restrict__ ko,
    unsigned short* __restrict__ vo, int M, int N, int K) {
  __shared__ unsigned short As[2][64][64];
  __shared__ unsigned short Bs[2][64][64];
  int m0 = blockIdx.x * 64, n0 = blockIdx.y * 64;
  int t = threadIdx.x;
  int wv = t >> 6, ln = t & 63, lg = ln >> 4, lr = ln & 15;
  int rsub = ln >> 3;
  int csw = ((ln & 7) ^ rsub) * 8;
  f32x4 acc[4];
#pragma unroll
  for (int c = 0; c < 4; ++c)
#pragma unroll
    for (int r = 0; r < 4; ++r) acc[c][r] = 0.f;

  const unsigned short* ag0 = A + (size_t)(m0 + wv * 16 + rsub) * K + csw;
  const unsigned short* ag1 = A + (size_t)(m0 + wv * 16 + 8 + rsub) * K + csw;
  const unsigned short* bg0 = Bm + (size_t)(n0 + wv * 16 + rsub) * K + csw;
  const unsigned short* bg1 = Bm + (size_t)(n0 + wv * 16 + 8 + rsub) * K + csw;

  glds16(ag0, &As[0][wv * 16][0]);
  glds16(ag1, &As[0][wv * 16 + 8][0]);
  glds16(bg0, &Bs[0][wv * 16][0]);
  glds16(bg1, &Bs[0][wv * 16 + 8][0]);

  int nk = K >> 6;
  for (int ki = 0; ki < nk; ++ki) {
    int cur = ki & 1;
    __syncthreads();
    if (ki + 1 < nk) {
      int nb = cur ^ 1;
      int ko_ = (ki + 1) * 64;
      glds16(ag0 + ko_, &As[nb][wv * 16][0]);
      glds16(ag1 + ko_, &As[nb][wv * 16 + 8][0]);
      glds16(bg0 + ko_, &Bs[nb][wv * 16][0]);
      glds16(bg1 + ko_, &Bs[nb][wv * 16 + 8][0]);
    }
#pragma unroll
    for (int kk = 0; kk < 64; kk += 32) {
      int arw = wv * 16 + lr;
      bf16x8 af = *(const bf16x8*)&As[cur][arw][sw8(arw, kk + lg * 8)];
#pragma unroll
      for (int c = 0; c < 4; ++c) {
        int brw = c * 16 + lr;
        bf16x8 bf = *(const bf16x8*)&Bs[cur][brw][sw8(brw, kk + lg * 8)];
        acc[c] = __builtin_amdgcn_mfma_f32_16x16x32_bf16(af, bf, acc[c], 0, 0, 0);
      }
    }
  }
#pragma unroll
  for (int c = 0; c < 4; ++c) {
    int C_ = n0 + c * 16 + lr;
    float bv = bias[C_];
#pragma unroll
    for (int r = 0; r < 4; ++r) {
      int R_ = m0 + wv * 16 + lg * 4 + r;
      float v = acc[c][r] + bv;
      if (LEAKY) v = v > 0.f ? v : 0.01f * v;
      if (RESID) v += resid[(size_t)R_ * N + C_];
      if (QKV) {
        int which = C_ >> 9, f = C_ & 511, h = f >> 6, d = f & 63;
        int b_ = R_ >> 11, s_ = R_ & 2047;
        if (which == 0) {
          qo[(((size_t)b_ * NH + h) * SQ + s_) * DHD + d] = f2bf(v * QSCALE);
        } else if (which == 1) {
          ko[(((size_t)b_ * NH + h) * SQ + s_) * DHD + d] = f2bf(v);
        } else {
          vo[(((size_t)b_ * NH + h) * DHD + d) * SQ + s_] = f2bf(v);  // V^T [b,h,d,s]
        }
      } else if (OUTF32) {
        outf[(size_t)R_ * N + C_] = v;
      } else {
        outh[(size_t)R_ * N + C_] = f2bf(v);
      }
    }
  }
}

// ---------------- GEMM 128x128 (QKV only): dbuf LDS via glds, 2x2 wave quadrants ----------------
template <bool QKV>
__global__ __launch_bounds__(256) void gemm128(
    const unsigned short* __restrict__ A, const unsigned short* __restrict__ Bm,
    const float* __restrict__ bias, unsigned short* __restrict__ qo,
    unsigned short* __restrict__ ko, unsigned short* __restrict__ vo,
    int M, int N, int K) {
  __shared__ unsigned short As[2][128][64];
  __shared__ unsigned short Bs[2][128][64];
  int m0 = blockIdx.x * 128, n0 = blockIdx.y * 128;
  int t = threadIdx.x;
  int wv = t >> 6, ln = t & 63, lg = ln >> 4, lr = ln & 15;
  int wr = wv >> 1, wc = wv & 1;
  int rsub = ln >> 3;
  int csw = ((ln & 7) ^ rsub) * 8;
  f32x4 acc[4][4];
#pragma unroll
  for (int m = 0; m < 4; ++m)
#pragma unroll
    for (int n = 0; n < 4; ++n)
#pragma unroll
      for (int r = 0; r < 4; ++r) acc[m][n][r] = 0.f;

  const unsigned short* agb = A + (size_t)(m0 + wv * 8 + rsub) * K + csw;
  const unsigned short* bgb = Bm + (size_t)(n0 + wv * 8 + rsub) * K + csw;

#pragma unroll
  for (int i = 0; i < 4; ++i) {
    glds16(agb + (size_t)(i * 32) * K, &As[0][i * 32 + wv * 8][0]);
    glds16(bgb + (size_t)(i * 32) * K, &Bs[0][i * 32 + wv * 8][0]);
  }

  int nk = K >> 6;
  for (int ki = 0; ki < nk; ++ki) {
    int cur = ki & 1;
    __syncthreads();
    if (ki + 1 < nk) {
      int nb = cur ^ 1;
      int ko_ = (ki + 1) * 64;
#pragma unroll
      for (int i = 0; i < 4; ++i) {
        glds16(agb + (size_t)(i * 32) * K + ko_, &As[nb][i * 32 + wv * 8][0]);
        glds16(bgb + (size_t)(i * 32) * K + ko_, &Bs[nb][i * 32 + wv * 8][0]);
      }
    }
#pragma unroll
    for (int kk = 0; kk < 64; kk += 32) {
      bf16x8 af[4], bfr[4];
#pragma unroll
      for (int m = 0; m < 4; ++m) {
        int arw = wr * 64 + m * 16 + lr;
        af[m] = *(const bf16x8*)&As[cur][arw][sw8(arw, kk + lg * 8)];
      }
#pragma unroll
      for (int n = 0; n < 4; ++n) {
        int brw = wc * 64 + n * 16 + lr;
        bfr[n] = *(const bf16x8*)&Bs[cur][brw][sw8(brw, kk + lg * 8)];
      }
#pragma unroll
      for (int m = 0; m < 4; ++m)
#pragma unroll
        for (int n = 0; n < 4; ++n)
          acc[m][n] = __builtin_amdgcn_mfma_f32_16x16x32_bf16(af[m], bfr[n], acc[m][n], 0, 0, 0);
    }
  }

#pragma unroll
  for (int n = 0; n < 4; ++n) {
    int C_ = n0 + wc * 64 + n * 16 + lr;
    float bv = bias[C_];
#pragma unroll
    for (int m = 0; m < 4; ++m) {
#pragma unroll
      for (int r = 0; r < 4; ++r) {
        int R_ = m0 + wr * 64 + m * 16 + lg * 4 + r;
        float v = acc[m][n][r] + bv;
        int which = C_ >> 9, f = C_ & 511, h = f >> 6, d = f & 63;
        int b_ = R_ >> 11, s_ = R_ & 2047;
        if (which == 0) {
          qo[(((size_t)b_ * NH + h) * SQ + s_) * DHD + d] = f2bf(v * QSCALE);
        } else if (which == 1) {
          ko[(((size_t)b_ * NH + h) * SQ + s_) * DHD + d] = f2bf(v);
        } else {
          vo[(((size_t)b_ * NH + h) * DHD + d) * SQ + s_] = f2bf(v);  // V^T [b,h,d,s]
        }
      }
    }
  }
}

// ---------------- Flash attention: paired q-tiles {31-bx heavy, bx light}, dbuf + glds ----------------
__global__ __launch_bounds__(256) void flash_kernel(
    const unsigned short* __restrict__ Q, const unsigned short* __restrict__ Kb,
    const unsigned short* __restrict__ Vt, unsigned short* __restrict__ ctx,
    float* __restrict__ mstat, float* __restrict__ lstat) {
  __shared__ unsigned short Ks[2][64][64];  // [buf][kpos][dh], swizzled (pre-swz source)
  __shared__ unsigned short Vs[2][64][64];  // [buf][dh][kpos], swizzled
  __shared__ unsigned short Ps[4][16][64];  // per-wave P [q][kpos], swizzled
  int h = blockIdx.y, b = blockIdx.z;
  int t = threadIdx.x, wv = t >> 6, ln = t & 63, lg = ln >> 4, lr = ln & 15;
  int rsub = ln >> 3;
  int csw = ((ln & 7) ^ rsub) * 8;
  size_t headoff = ((size_t)b * NH + h) * SQ;
  const unsigned short* kg0 = Kb + (headoff + wv * 16 + rsub) * DHD + csw;
  const unsigned short* kg1 = Kb + (headoff + wv * 16 + 8 + rsub) * DHD + csw;
  const unsigned short* vg0 = Vt + (((size_t)b * NH + h) * DHD + wv * 16 + rsub) * SQ + csw;
  const unsigned short* vg1 = Vt + (((size_t)b * NH + h) * DHD + wv * 16 + 8 + rsub) * SQ + csw;

  // ones B-fragment: accumulator col 0 = row-sum of P
  bf16x8 vones;
#pragma unroll
  for (int j = 0; j < 8; ++j) vones[j] = (lr == 0) ? (short)0x3F80 : (short)0;

  for (int half = 0; half < 2; ++half) {
    int qt = half ? blockIdx.x : (31 - blockIdx.x);  // heavy half first
    int qb = qt * 64;
    const unsigned short* qrow = Q + (headoff + qb + wv * 16 + lr) * DHD;
    bf16x8 aq0 = *(const bf16x8*)(qrow + lg * 8);
    bf16x8 aq1 = *(const bf16x8*)(qrow + 32 + lg * 8);

    f32x4 cacc[4], lacc;
#pragma unroll
    for (int nd = 0; nd < 4; ++nd)
#pragma unroll
      for (int r = 0; r < 4; ++r) cacc[nd][r] = 0.f;
#pragma unroll
    for (int r = 0; r < 4; ++r) lacc[r] = 0.f;
    float mrun[4];
#pragma unroll
    for (int r = 0; r < 4; ++r) mrun[r] = -__builtin_inff();

    int nkt = qt + 1;
    __syncthreads();  // previous half's LDS reads fully done
    glds16(kg0, &Ks[0][wv * 16][0]);
    glds16(kg1, &Ks[0][wv * 16 + 8][0]);
    glds16(vg0, &Vs[0][wv * 16][0]);
    glds16(vg1, &Vs[0][wv * 16 + 8][0]);

    for (int kt = 0; kt < nkt; ++kt) {
      int cur = kt & 1;
      __syncthreads();  // drains glds -> buf[cur] ready
      if (kt + 1 < nkt) {
        int nb = cur ^ 1;
        size_t ko_ = (size_t)(kt + 1) * 64;
        glds16(kg0 + ko_ * DHD, &Ks[nb][wv * 16][0]);
        glds16(kg1 + ko_ * DHD, &Ks[nb][wv * 16 + 8][0]);
        glds16(vg0 + ko_, &Vs[nb][wv * 16][0]);
        glds16(vg1 + ko_, &Vs[nb][wv * 16 + 8][0]);
      }

      // QK^T (Q pre-scaled; scores in log2 units)
      float sv[4][4];
      __builtin_amdgcn_s_setprio(1);
#pragma unroll
      for (int nt = 0; nt < 4; ++nt) {
        f32x4 sf;
#pragma unroll
        for (int r = 0; r < 4; ++r) sf[r] = 0.f;
        int brw = nt * 16 + lr;
        bf16x8 bk0 = *(const bf16x8*)&Ks[cur][brw][sw8(brw, lg * 8)];
        bf16x8 bk1 = *(const bf16x8*)&Ks[cur][brw][sw8(brw, 32 + lg * 8)];
        sf = __builtin_amdgcn_mfma_f32_16x16x32_bf16(aq0, bk0, sf, 0, 0, 0);
        sf = __builtin_amdgcn_mfma_f32_16x16x32_bf16(aq1, bk1, sf, 0, 0, 0);
#pragma unroll
        for (int r = 0; r < 4; ++r) sv[nt][r] = sf[r];
      }
      __builtin_amdgcn_s_setprio(0);
      if (kt == nkt - 1) {
        int kbase = kt * 64;
#pragma unroll
        for (int nt = 0; nt < 4; ++nt) {
          int kcol = kbase + nt * 16 + lr;
#pragma unroll
          for (int r = 0; r < 4; ++r) {
            int qr = qb + wv * 16 + lg * 4 + r;
            if (kcol > qr) sv[nt][r] = -__builtin_inff();
          }
        }
      }

      // online softmax: lane-local defer-max gate
      float lmax[4];
      bool need = false;
#pragma unroll
      for (int r = 0; r < 4; ++r) {
        lmax[r] = fmaxf(fmaxf(sv[0][r], sv[1][r]), fmaxf(sv[2][r], sv[3][r]));
        need |= (lmax[r] > mrun[r] + 8.f);
      }
      if (__any(need)) {
#pragma unroll
        for (int r = 0; r < 4; ++r) {
          float tm = lmax[r];
#pragma unroll
          for (int m = 1; m < 16; m <<= 1) tm = fmaxf(tm, __shfl_xor(tm, m));
          float mn = fmaxf(mrun[r], tm);
          float sc = exp2f(mrun[r] - mn);
          mrun[r] = mn;
          lacc[r] *= sc;
#pragma unroll
          for (int nd = 0; nd < 4; ++nd) cacc[nd][r] *= sc;
        }
      }
      // P-store: truncating f32->bf16 (1 op); downward bias cancels via l (ones-MFMA
      // sums the SAME truncated values), so O = sum(P V)/sum(P) is unbiased to 1st order.
#pragma unroll
      for (int r = 0; r < 4; ++r) {
        int prow = lg * 4 + r;
#pragma unroll
        for (int nt = 0; nt < 4; ++nt) {
          float p = exp2f(sv[nt][r] - mrun[r]);
          Ps[wv][prow][sw8(prow, nt * 16 + lr)] =
              (unsigned short)(__float_as_uint(p) >> 16);
        }
      }

      // PV
      bf16x8 pf0 = *(const bf16x8*)&Ps[wv][lr][sw8(lr, lg * 8)];
      bf16x8 pf1 = *(const bf16x8*)&Ps[wv][lr][sw8(lr, 32 + lg * 8)];
      __builtin_amdgcn_s_setprio(1);
      lacc = __builtin_amdgcn_mfma_f32_16x16x32_bf16(pf0, vones, lacc, 0, 0, 0);
      lacc = __builtin_amdgcn_mfma_f32_16x16x32_bf16(pf1, vones, lacc, 0, 0, 0);
#pragma unroll
      for (int nd = 0; nd < 4; ++nd) {
        int vrw = nd * 16 + lr;
        bf16x8 vf0 = *(const bf16x8*)&Vs[cur][vrw][sw8(vrw, lg * 8)];
        bf16x8 vf1 = *(const bf16x8*)&Vs[cur][vrw][sw8(vrw, 32 + lg * 8)];
        cacc[nd] = __builtin_amdgcn_mfma_f32_16x16x32_bf16(pf0, vf0, cacc[nd], 0, 0, 0);
        cacc[nd] = __builtin_amdgcn_mfma_f32_16x16x32_bf16(pf1, vf1, cacc[nd], 0, 0, 0);
      }
      __builtin_amdgcn_s_setprio(0);
    }

    float inv[4];
#pragma unroll
    for (int r = 0; r < 4; ++r) inv[r] = 1.f / __shfl(lacc[r], ln & 48);
#pragma unroll
    for (int nd = 0; nd < 4; ++nd)
#pragma unroll
      for (int r = 0; r < 4; ++r) {
        size_t dst = ((size_t)b * SQ + qb + wv * 16 + lg * 4 + r) * EM + h * DHD + nd * 16 + lr;
        ctx[dst] = f2bf(cacc[nd][r] * inv[r]);
      }
    if (lr == 0) {
#pragma unroll
      for (int r = 0; r < 4; ++r) {
        int row = qb + wv * 16 + lg * 4 + r;
        mstat[headoff + row] = mrun[r];            // log2 units
        lstat[headoff + row] = 0.125f * inv[r];    // 1/(H*l): attnw uses directly
      }
    }
  }
}

// ---------------- attn_weights: 2 k-tiles per block, K dbuf over heads + Q/m/l pipeline ----------------
__global__ __launch_bounds__(256) void attnw_kernel(
    const unsigned short* __restrict__ Q, const unsigned short* __restrict__ Kb,
    const float* __restrict__ mstat, const float* __restrict__ lstat,
    float* __restrict__ aw) {
  int kt2 = blockIdx.x, qt = blockIdx.y, b = blockIdx.z;
  int qb = qt * 64, kb = kt2 * 128;
  int t = threadIdx.x;
  float* tile = aw + ((size_t)b * SQ + qb) * SQ + kb;
  if (2 * kt2 > qt) {  // both 64-col tiles fully masked -> exact zeros (64x128 region)
    int row = t >> 2, cbase = (t & 3) * 32;
    f32x4 z;
#pragma unroll
    for (int j = 0; j < 4; ++j) z[j] = 0.f;
    float* p = tile + (size_t)row * SQ + cbase;
#pragma unroll
    for (int j = 0; j < 8; ++j) *(f32x4*)(p + j * 4) = z;
    return;
  }
  __shared__ unsigned short Ks[2][2][64][64];  // [dbuf][tile][kpos][dh], 32 KB
  int wv = t >> 6, ln = t & 63, lg = ln >> 4, lr = ln & 15;
  int rsub = ln >> 3;
  int csw = ((ln & 7) ^ rsub) * 8;
  size_t khstride = (size_t)SQ * DHD;
  const unsigned short* kg00 = Kb + (((size_t)b * NH) * SQ + kb + wv * 16 + rsub) * DHD + csw;
  const unsigned short* kg01 = kg00 + (size_t)8 * DHD;
  const unsigned short* kg10 = kg00 + (size_t)64 * DHD;  // second tile rows
  const unsigned short* kg11 = kg00 + (size_t)72 * DHD;
  const unsigned short* qg = Q + (((size_t)b * NH) * SQ + qb + wv * 16 + lr) * DHD + lg * 8;
  size_t mbase = (size_t)b * NH * SQ + qb + wv * 16 + lg * 4;

  // prologue: issue K head0 (both tiles) -> buf0; Q/m/l for head0 (cur) and head1 (next)
  glds16(kg00, &Ks[0][0][wv * 16][0]);
  glds16(kg01, &Ks[0][0][wv * 16 + 8][0]);
  glds16(kg10, &Ks[0][1][wv * 16][0]);
  glds16(kg11, &Ks[0][1][wv * 16 + 8][0]);

  bf16x8 aqc0 = *(const bf16x8*)qg;
  bf16x8 aqc1 = *(const bf16x8*)(qg + 32);
  bf16x8 aqn0 = *(const bf16x8*)(qg + khstride);
  bf16x8 aqn1 = *(const bf16x8*)(qg + khstride + 32);
  float mmc[4], lic[4], mmn[4], lin[4];
#pragma unroll
  for (int r = 0; r < 4; ++r) {
    mmc[r] = mstat[mbase + r];
    lic[r] = lstat[mbase + r];
    mmn[r] = mstat[mbase + SQ + r];
    lin[r] = lstat[mbase + SQ + r];
  }

  f32x4 facc[2][4];
#pragma unroll
  for (int j = 0; j < 2; ++j)
#pragma unroll
    for (int nt = 0; nt < 4; ++nt)
#pragma unroll
      for (int r = 0; r < 4; ++r) facc[j][nt][r] = 0.f;

  for (int h = 0; h < NH; ++h) {
    int cur = h & 1;
    __syncthreads();  // drains glds -> Ks[cur] ready
    if (h + 1 < NH) {  // issue next head's K (both tiles) into alternate buffer
      size_t ho = (size_t)(h + 1) * khstride;
      glds16(kg00 + ho, &Ks[cur ^ 1][0][wv * 16][0]);
      glds16(kg01 + ho, &Ks[cur ^ 1][0][wv * 16 + 8][0]);
      glds16(kg10 + ho, &Ks[cur ^ 1][1][wv * 16][0]);
      glds16(kg11 + ho, &Ks[cur ^ 1][1][wv * 16 + 8][0]);
    }

    // compute head h: both tiles with shared Q (no masking here)
#pragma unroll
    for (int nt = 0; nt < 4; ++nt) {
      int brw = nt * 16 + lr;
      f32x4 sf0, sf1;
#pragma unroll
      for (int r = 0; r < 4; ++r) { sf0[r] = 0.f; sf1[r] = 0.f; }
      bf16x8 bk00 = *(const bf16x8*)&Ks[cur][0][brw][sw8(brw, lg * 8)];
      bf16x8 bk01 = *(const bf16x8*)&Ks[cur][0][brw][sw8(brw, 32 + lg * 8)];
      bf16x8 bk10 = *(const bf16x8*)&Ks[cur][1][brw][sw8(brw, lg * 8)];
      bf16x8 bk11 = *(const bf16x8*)&Ks[cur][1][brw][sw8(brw, 32 + lg * 8)];
      sf0 = __builtin_amdgcn_mfma_f32_16x16x32_bf16(aqc0, bk00, sf0, 0, 0, 0);
      sf1 = __builtin_amdgcn_mfma_f32_16x16x32_bf16(aqc0, bk10, sf1, 0, 0, 0);
      sf0 = __builtin_amdgcn_mfma_f32_16x16x32_bf16(aqc1, bk01, sf0, 0, 0, 0);
      sf1 = __builtin_amdgcn_mfma_f32_16x16x32_bf16(aqc1, bk11, sf1, 0, 0, 0);
#pragma unroll
      for (int r = 0; r < 4; ++r) {
        facc[0][nt][r] += exp2f(sf0[r] - mmc[r]) * lic[r];
        facc[1][nt][r] += exp2f(sf1[r] - mmc[r]) * lic[r];
      }
    }

    // rotate Q/m/l pipeline; issue loads for head h+2
    aqc0 = aqn0; aqc1 = aqn1;
#pragma unroll
    for (int r = 0; r < 4; ++r) { mmc[r] = mmn[r]; lic[r] = lin[r]; }
    if (h + 2 < NH) {
      aqn0 = *(const bf16x8*)(qg + (size_t)(h + 2) * khstride);
      aqn1 = *(const bf16x8*)(qg + (size_t)(h + 2) * khstride + 32);
#pragma unroll
      for (int r = 0; r < 4; ++r) {
        mmn[r] = mstat[mbase + (size_t)(h + 2) * SQ + r];
        lin[r] = lstat[mbase + (size_t)(h + 2) * SQ + r];
      }
    }
  }

  // write; masking applied once per tile: full-mask / diagonal / none
#pragma unroll
  for (int j = 0; j < 2; ++j) {
    int ktj = 2 * kt2 + j;
    bool fullmask = (ktj > qt);
    bool dg = (ktj == qt);
#pragma unroll
    for (int nt = 0; nt < 4; ++nt) {
      int kc = kb + j * 64 + nt * 16 + lr;
#pragma unroll
      for (int r = 0; r < 4; ++r) {
        int qr = qb + wv * 16 + lg * 4 + r;
        float v = (fullmask || (dg && kc > qr)) ? 0.f : facc[j][nt][r];
        tile[(size_t)(wv * 16 + lg * 4 + r) * SQ + j * 64 + nt * 16 + lr] = v;
      }
    }
  }
}

extern "C" void kernel_launch(void* const* d_in, const int* in_sizes, int n_in,
                              void* d_out, int out_size, void* d_ws, size_t ws_size,
                              hipStream_t stream) {
  (void)in_sizes; (void)n_in; (void)out_size; (void)ws_size;
  const float* x = (const float*)d_in[0];
  const float* ln1g = (const float*)d_in[1];
  const float* ln1b = (const float*)d_in[2];
  const float* wqkv = (const float*)d_in[3];
  const float* bqkv = (const float*)d_in[4];
  const float* wout = (const float*)d_in[5];
  const float* bout = (const float*)d_in[6];
  const float* ln2g = (const float*)d_in[7];
  const float* ln2b = (const float*)d_in[8];
  const float* wfc1 = (const float*)d_in[9];
  const float* bfc1 = (const float*)d_in[10];
  const float* wfc2 = (const float*)d_in[11];
  const float* bfc2 = (const float*)d_in[12];

  char* ws = (char*)d_ws;
  unsigned short* zctx = (unsigned short*)(ws);               // z (bf16), later reused as ctx
  unsigned short* qb_ = (unsigned short*)(ws + 8388608);      // later reused as LN2 out
  unsigned short* kb_ = (unsigned short*)(ws + 16777216);     // later reused as fc1 out
  unsigned short* vb_ = (unsigned short*)(ws + 25165824);     // V^T [b,h,d,s]
  float* z2 = (float*)(ws + 33554432);                        // fp32 residual stream
  float* mstat = (float*)(ws + 50331648);
  float* lstat = (float*)(ws + 50593792);
  unsigned short* wqkv_h = (unsigned short*)(ws + 50855936);
  unsigned short* wout_h = (unsigned short*)(ws + 52428800);
  unsigned short* wfc1_h = (unsigned short*)(ws + 52953088);
  unsigned short* wfc2_h = (unsigned short*)(ws + 53477376);
  unsigned short* y1 = qb_;
  unsigned short* h1 = kb_;

  float* outy = (float*)d_out;
  float* outw = outy + (size_t)NB * SQ * EM;

  f2bf4_kernel<<<768, 256, 0, stream>>>(wqkv, wout, wfc1, wfc2,
                                        wqkv_h, wout_h, wfc1_h, wfc2_h);

  ln_kernel<<<2048, 256, 0, stream>>>(x, ln1g, ln1b, zctx);
  gemm128<true><<<dim3(64, 12), 256, 0, stream>>>(
      zctx, wqkv_h, bqkv, qb_, kb_, vb_, 8192, 1536, 512);
  flash_kernel<<<dim3(16, 8, 4), 256, 0, stream>>>(qb_, kb_, vb_, zctx, mstat, lstat);
  attnw_kernel<<<dim3(16, 32, 4), 256, 0, stream>>>(qb_, kb_, mstat, lstat, outw);
  gemm64<false, true, true, false><<<dim3(128, 8), 256, 0, stream>>>(
      zctx, wout_h, bout, x, z2, nullptr, nullptr, nullptr, nullptr, 8192, 512, 512);
  ln_kernel<<<2048, 256, 0, stream>>>(z2, ln2g, ln2b, y1);
  gemm64<true, false, false, false><<<dim3(128, 8), 256, 0, stream>>>(
      y1, wfc1_h, bfc1, nullptr, nullptr, h1, nullptr, nullptr, nullptr, 8192, 512, 512);
  gemm64<false, true, true, false><<<dim3(128, 8), 256, 0, stream>>>(
      h1, wfc2_h, bfc2, z2, outy, nullptr, nullptr, nullptr, nullptr, 8192, 512, 512);
}

// Round 18
// 184.805 us; speedup vs baseline: 1.1358x; 1.0077x over previous
//
#include <hip/hip_runtime.h>

typedef short bf16x8 __attribute__((ext_vector_type(8)));
typedef float f32x4 __attribute__((ext_vector_type(4)));
typedef unsigned short u16x8 __attribute__((ext_vector_type(8)));

#define NB 4
#define SQ 2048
#define EM 512
#define NH 8
#define DHD 64
// 1/sqrt(DH) * log2(e): Q pre-scaled so softmax uses exp2
#define QSCALE 0.1803368801111731f

__device__ __forceinline__ unsigned short f2bf(float x) {
  unsigned u = __float_as_uint(x);
  u += 0x7FFFu + ((u >> 16) & 1u);
  return (unsigned short)(u >> 16);
}

__device__ __forceinline__ int sw8(int row, int col8) { return col8 ^ ((row & 7) << 3); }
__device__ __forceinline__ int sw16(int row, int col8) { return col8 ^ ((row & 15) << 3); }

// async global->LDS, 16B/lane; LDS dest = wave-uniform base + lane*16 (linear).
// Swizzled storage achieved by pre-swizzling the per-lane GLOBAL source address.
__device__ __forceinline__ void glds16(const void* g, void* l) {
  __builtin_amdgcn_global_load_lds(
      (const __attribute__((address_space(1))) void*)g,
      (__attribute__((address_space(3))) void*)l, 16, 0, 0);
}

// ---------------- fused fp32 -> bf16 convert (all 4 weight tensors) ----------------
__global__ __launch_bounds__(256) void f2bf4_kernel(
    const float* __restrict__ w0, const float* __restrict__ w1,
    const float* __restrict__ w2, const float* __restrict__ w3,
    unsigned short* __restrict__ o0, unsigned short* __restrict__ o1,
    unsigned short* __restrict__ o2, unsigned short* __restrict__ o3) {
  int i = (blockIdx.x * 256 + threadIdx.x) * 8;
  const float* src;
  unsigned short* dst;
  int off;
  if (i < 786432) { src = w0; dst = o0; off = i; }
  else if (i < 1048576) { src = w1; dst = o1; off = i - 786432; }
  else if (i < 1310720) { src = w2; dst = o2; off = i - 1048576; }
  else { src = w3; dst = o3; off = i - 1310720; }
  f32x4 a = *(const f32x4*)(src + off);
  f32x4 b = *(const f32x4*)(src + off + 4);
  u16x8 o;
#pragma unroll
  for (int j = 0; j < 4; ++j) { o[j] = f2bf(a[j]); o[j + 4] = f2bf(b[j]); }
  *(u16x8*)(dst + off) = o;
}

// ---------------- LayerNorm (row = E=512), fp32 in -> bf16 out ----------------
__global__ __launch_bounds__(256) void ln_kernel(const float* __restrict__ x,
                                                 const float* __restrict__ g,
                                                 const float* __restrict__ bb,
                                                 unsigned short* __restrict__ out) {
  int tid = threadIdx.x;
  int row = blockIdx.x * 4 + (tid >> 6);
  int lane = tid & 63;
  size_t base = (size_t)row * EM + lane * 8;
  f32x4 v0 = *(const f32x4*)(x + base);
  f32x4 v1 = *(const f32x4*)(x + base + 4);
  float s = 0.f, q = 0.f;
#pragma unroll
  for (int j = 0; j < 4; ++j) { s += v0[j] + v1[j]; q += v0[j] * v0[j] + v1[j] * v1[j]; }
#pragma unroll
  for (int m = 1; m < 64; m <<= 1) { s += __shfl_xor(s, m); q += __shfl_xor(q, m); }
  float mean = s * (1.f / EM);
  float var = q * (1.f / EM) - mean * mean;
  float rs = rsqrtf(var + 1e-5f);
  f32x4 g0 = *(const f32x4*)(g + lane * 8), g1 = *(const f32x4*)(g + lane * 8 + 4);
  f32x4 b0 = *(const f32x4*)(bb + lane * 8), b1 = *(const f32x4*)(bb + lane * 8 + 4);
  u16x8 o;
#pragma unroll
  for (int j = 0; j < 4; ++j) {
    o[j] = f2bf((v0[j] - mean) * rs * g0[j] + b0[j]);
    o[j + 4] = f2bf((v1[j] - mean) * rs * g1[j] + b1[j]);
  }
  *(u16x8*)(out + base) = o;
}

// ---------------- GEMM 64x64: dbuf LDS via global_load_lds (1 barrier/iter) ----------------
template <bool LEAKY, bool RESID, bool OUTF32, bool QKV>
__global__ __launch_bounds__(256) void gemm64(
    const unsigned short* __restrict__ A, const unsigned short* __restrict__ Bm,
    const float* __restrict__ bias, const float* __restrict__ resid,
    float* __restrict__ outf, unsigned short* __restrict__ outh,
    unsigned short* __restrict__ qo, unsigned short* __restrict__ ko,
    unsigned short* __restrict__ vo, int M, int N, int K) {
  __shared__ unsigned short As[2][64][64];
  __shared__ unsigned short Bs[2][64][64];
  int m0 = blockIdx.x * 64, n0 = blockIdx.y * 64;
  int t = threadIdx.x;
  int wv = t >> 6, ln = t & 63, lg = ln >> 4, lr = ln & 15;
  int rsub = ln >> 3;
  int csw = ((ln & 7) ^ rsub) * 8;
  f32x4 acc[4];
#pragma unroll
  for (int c = 0; c < 4; ++c)
#pragma unroll
    for (int r = 0; r < 4; ++r) acc[c][r] = 0.f;

  const unsigned short* ag0 = A + (size_t)(m0 + wv * 16 + rsub) * K + csw;
  const unsigned short* ag1 = A + (size_t)(m0 + wv * 16 + 8 + rsub) * K + csw;
  const unsigned short* bg0 = Bm + (size_t)(n0 + wv * 16 + rsub) * K + csw;
  const unsigned short* bg1 = Bm + (size_t)(n0 + wv * 16 + 8 + rsub) * K + csw;

  glds16(ag0, &As[0][wv * 16][0]);
  glds16(ag1, &As[0][wv * 16 + 8][0]);
  glds16(bg0, &Bs[0][wv * 16][0]);
  glds16(bg1, &Bs[0][wv * 16 + 8][0]);

  int nk = K >> 6;
  for (int ki = 0; ki < nk; ++ki) {
    int cur = ki & 1;
    __syncthreads();
    if (ki + 1 < nk) {
      int nb = cur ^ 1;
      int ko_ = (ki + 1) * 64;
      glds16(ag0 + ko_, &As[nb][wv * 16][0]);
      glds16(ag1 + ko_, &As[nb][wv * 16 + 8][0]);
      glds16(bg0 + ko_, &Bs[nb][wv * 16][0]);
      glds16(bg1 + ko_, &Bs[nb][wv * 16 + 8][0]);
    }
#pragma unroll
    for (int kk = 0; kk < 64; kk += 32) {
      int arw = wv * 16 + lr;
      bf16x8 af = *(const bf16x8*)&As[cur][arw][sw8(arw, kk + lg * 8)];
#pragma unroll
      for (int c = 0; c < 4; ++c) {
        int brw = c * 16 + lr;
        bf16x8 bf = *(const bf16x8*)&Bs[cur][brw][sw8(brw, kk + lg * 8)];
        acc[c] = __builtin_amdgcn_mfma_f32_16x16x32_bf16(af, bf, acc[c], 0, 0, 0);
      }
    }
  }
#pragma unroll
  for (int c = 0; c < 4; ++c) {
    int C_ = n0 + c * 16 + lr;
    float bv = bias[C_];
#pragma unroll
    for (int r = 0; r < 4; ++r) {
      int R_ = m0 + wv * 16 + lg * 4 + r;
      float v = acc[c][r] + bv;
      if (LEAKY) v = v > 0.f ? v : 0.01f * v;
      if (RESID) v += resid[(size_t)R_ * N + C_];
      if (QKV) {
        int which = C_ >> 9, f = C_ & 511, h = f >> 6, d = f & 63;
        int b_ = R_ >> 11, s_ = R_ & 2047;
        if (which == 0) {
          qo[(((size_t)b_ * NH + h) * SQ + s_) * DHD + d] = f2bf(v * QSCALE);
        } else if (which == 1) {
          ko[(((size_t)b_ * NH + h) * SQ + s_) * DHD + d] = f2bf(v);
        } else {
          vo[(((size_t)b_ * NH + h) * DHD + d) * SQ + s_] = f2bf(v);  // V^T [b,h,d,s]
        }
      } else if (OUTF32) {
        outf[(size_t)R_ * N + C_] = v;
      } else {
        outh[(size_t)R_ * N + C_] = f2bf(v);
      }
    }
  }
}

// ---------------- GEMM 128x128 (QKV only): dbuf LDS via glds, 2x2 wave quadrants ----------------
template <bool QKV>
__global__ __launch_bounds__(256) void gemm128(
    const unsigned short* __restrict__ A, const unsigned short* __restrict__ Bm,
    const float* __restrict__ bias, unsigned short* __restrict__ qo,
    unsigned short* __restrict__ ko, unsigned short* __restrict__ vo,
    int M, int N, int K) {
  __shared__ unsigned short As[2][128][64];
  __shared__ unsigned short Bs[2][128][64];
  int m0 = blockIdx.x * 128, n0 = blockIdx.y * 128;
  int t = threadIdx.x;
  int wv = t >> 6, ln = t & 63, lg = ln >> 4, lr = ln & 15;
  int wr = wv >> 1, wc = wv & 1;
  int rsub = ln >> 3;
  int csw = ((ln & 7) ^ rsub) * 8;
  f32x4 acc[4][4];
#pragma unroll
  for (int m = 0; m < 4; ++m)
#pragma unroll
    for (int n = 0; n < 4; ++n)
#pragma unroll
      for (int r = 0; r < 4; ++r) acc[m][n][r] = 0.f;

  const unsigned short* agb = A + (size_t)(m0 + wv * 8 + rsub) * K + csw;
  const unsigned short* bgb = Bm + (size_t)(n0 + wv * 8 + rsub) * K + csw;

#pragma unroll
  for (int i = 0; i < 4; ++i) {
    glds16(agb + (size_t)(i * 32) * K, &As[0][i * 32 + wv * 8][0]);
    glds16(bgb + (size_t)(i * 32) * K, &Bs[0][i * 32 + wv * 8][0]);
  }

  int nk = K >> 6;
  for (int ki = 0; ki < nk; ++ki) {
    int cur = ki & 1;
    __syncthreads();
    if (ki + 1 < nk) {
      int nb = cur ^ 1;
      int ko_ = (ki + 1) * 64;
#pragma unroll
      for (int i = 0; i < 4; ++i) {
        glds16(agb + (size_t)(i * 32) * K + ko_, &As[nb][i * 32 + wv * 8][0]);
        glds16(bgb + (size_t)(i * 32) * K + ko_, &Bs[nb][i * 32 + wv * 8][0]);
      }
    }
#pragma unroll
    for (int kk = 0; kk < 64; kk += 32) {
      bf16x8 af[4], bfr[4];
#pragma unroll
      for (int m = 0; m < 4; ++m) {
        int arw = wr * 64 + m * 16 + lr;
        af[m] = *(const bf16x8*)&As[cur][arw][sw8(arw, kk + lg * 8)];
      }
#pragma unroll
      for (int n = 0; n < 4; ++n) {
        int brw = wc * 64 + n * 16 + lr;
        bfr[n] = *(const bf16x8*)&Bs[cur][brw][sw8(brw, kk + lg * 8)];
      }
#pragma unroll
      for (int m = 0; m < 4; ++m)
#pragma unroll
        for (int n = 0; n < 4; ++n)
          acc[m][n] = __builtin_amdgcn_mfma_f32_16x16x32_bf16(af[m], bfr[n], acc[m][n], 0, 0, 0);
    }
  }

#pragma unroll
  for (int n = 0; n < 4; ++n) {
    int C_ = n0 + wc * 64 + n * 16 + lr;
    float bv = bias[C_];
#pragma unroll
    for (int m = 0; m < 4; ++m) {
#pragma unroll
      for (int r = 0; r < 4; ++r) {
        int R_ = m0 + wr * 64 + m * 16 + lg * 4 + r;
        float v = acc[m][n][r] + bv;
        int which = C_ >> 9, f = C_ & 511, h = f >> 6, d = f & 63;
        int b_ = R_ >> 11, s_ = R_ & 2047;
        if (which == 0) {
          qo[(((size_t)b_ * NH + h) * SQ + s_) * DHD + d] = f2bf(v * QSCALE);
        } else if (which == 1) {
          ko[(((size_t)b_ * NH + h) * SQ + s_) * DHD + d] = f2bf(v);
        } else {
          vo[(((size_t)b_ * NH + h) * DHD + d) * SQ + s_] = f2bf(v);  // V^T [b,h,d,s]
        }
      }
    }
  }
}

// ---------------- Flash attention: KVBLK=128, paired q-tiles {31-bx, bx}, dbuf + glds ----------------
// Per phase: 128-row K tile + 64x128 V^T tile, one barrier, one softmax pass over 128 cols.
// Pair sums to 17 iterations for every block.
__global__ __launch_bounds__(256) void flash_kernel(
    const unsigned short* __restrict__ Q, const unsigned short* __restrict__ Kb,
    const unsigned short* __restrict__ Vt, unsigned short* __restrict__ ctx,
    float* __restrict__ mstat, float* __restrict__ lstat) {
  __shared__ unsigned short Ks[2][128][64];   // [buf][kpos][dh], sw8-swizzled
  __shared__ unsigned short Vs[2][64][128];   // [buf][dh][kpos], sw16-swizzled
  __shared__ unsigned short Ps[4][16][128];   // per-wave P [q][kpos], sw16-swizzled
  int h = blockIdx.y, b = blockIdx.z;
  int t = threadIdx.x, wv = t >> 6, ln = t & 63, lg = ln >> 4, lr = ln & 15;
  size_t headoff = ((size_t)b * NH + h) * SQ;
  size_t vbase = ((size_t)b * NH + h) * DHD;

  // K staging: 4 glds/wave, rows wv*32+g*8+(ln>>3); src pre-swizzle (ln&7)^(ln>>3)
  int cswK = ((ln & 7) ^ (ln >> 3)) * 8;
  const unsigned short* kgb = Kb + (headoff + wv * 32 + (ln >> 3)) * DHD + cswK;
  // V staging: 4 glds/wave, d-rows wv*16+g*4+(ln>>4); src pre-swizzle (ln&15)^(g*4+(ln>>4))
  int vrow4 = ln >> 4;  // 0..3
  const unsigned short* vgb = Vt + (vbase + wv * 16 + vrow4) * SQ;
  int vcsw[4];
#pragma unroll
  for (int g = 0; g < 4; ++g) vcsw[g] = ((ln & 15) ^ (g * 4 + vrow4)) * 8;

  // ones B-fragment: accumulator col 0 = row-sum of P
  bf16x8 vones;
#pragma unroll
  for (int j = 0; j < 8; ++j) vones[j] = (lr == 0) ? (short)0x3F80 : (short)0;

  for (int half = 0; half < 2; ++half) {
    int qt = half ? blockIdx.x : (31 - blockIdx.x);  // heavy half first
    int qb = qt * 64;
    const unsigned short* qrow = Q + (headoff + qb + wv * 16 + lr) * DHD;
    bf16x8 aq0 = *(const bf16x8*)(qrow + lg * 8);
    bf16x8 aq1 = *(const bf16x8*)(qrow + 32 + lg * 8);

    f32x4 cacc[4], lacc;
#pragma unroll
    for (int nd = 0; nd < 4; ++nd)
#pragma unroll
      for (int r = 0; r < 4; ++r) cacc[nd][r] = 0.f;
#pragma unroll
    for (int r = 0; r < 4; ++r) lacc[r] = 0.f;
    float mrun[4];
#pragma unroll
    for (int r = 0; r < 4; ++r) mrun[r] = -__builtin_inff();

    int nkt = (qt + 2) >> 1;  // 128-wide k-tiles covering rows 0..qb+63
    __syncthreads();  // previous half's LDS reads fully done
    // prologue: issue tile 0 into buf0 (8 glds/wave)
#pragma unroll
    for (int g = 0; g < 4; ++g) {
      glds16(kgb + (size_t)(g * 8) * DHD, &Ks[0][wv * 32 + g * 8][0]);
      glds16(vgb + (size_t)(g * 4) * SQ + vcsw[g], &Vs[0][wv * 16 + g * 4][0]);
    }

    for (int kt = 0; kt < nkt; ++kt) {
      int cur = kt & 1;
      int kb = kt * 128;
      __syncthreads();  // drains glds -> buf[cur] ready
      if (kt + 1 < nkt) {  // issue next tile into alternate buffer
        int nb = cur ^ 1;
        size_t ko_ = (size_t)(kt + 1) * 128;
#pragma unroll
        for (int g = 0; g < 4; ++g) {
          glds16(kgb + (ko_ + g * 8) * DHD, &Ks[nb][wv * 32 + g * 8][0]);
          glds16(vgb + (size_t)(g * 4) * SQ + ko_ + vcsw[g], &Vs[nb][wv * 16 + g * 4][0]);
        }
      }

      // QK^T over 128 cols (Q pre-scaled; scores in log2 units)
      float sv[8][4];
      __builtin_amdgcn_s_setprio(1);
#pragma unroll
      for (int nt = 0; nt < 8; ++nt) {
        f32x4 sf;
#pragma unroll
        for (int r = 0; r < 4; ++r) sf[r] = 0.f;
        int brw = nt * 16 + lr;
        bf16x8 bk0 = *(const bf16x8*)&Ks[cur][brw][sw8(brw, lg * 8)];
        bf16x8 bk1 = *(const bf16x8*)&Ks[cur][brw][sw8(brw, 32 + lg * 8)];
        sf = __builtin_amdgcn_mfma_f32_16x16x32_bf16(aq0, bk0, sf, 0, 0, 0);
        sf = __builtin_amdgcn_mfma_f32_16x16x32_bf16(aq1, bk1, sf, 0, 0, 0);
#pragma unroll
        for (int r = 0; r < 4; ++r) sv[nt][r] = sf[r];
      }
      __builtin_amdgcn_s_setprio(0);
      if (kt == nkt - 1) {  // tile containing the diagonal: causal mask
#pragma unroll
        for (int nt = 0; nt < 8; ++nt) {
          int kcol = kb + nt * 16 + lr;
#pragma unroll
          for (int r = 0; r < 4; ++r) {
            int qr = qb + wv * 16 + lg * 4 + r;
            if (kcol > qr) sv[nt][r] = -__builtin_inff();
          }
        }
      }

      // online softmax over 128 cols: lane-local defer-max gate
      float lmax[4];
      bool need = false;
#pragma unroll
      for (int r = 0; r < 4; ++r) {
        float m0_ = fmaxf(fmaxf(sv[0][r], sv[1][r]), fmaxf(sv[2][r], sv[3][r]));
        float m1_ = fmaxf(fmaxf(sv[4][r], sv[5][r]), fmaxf(sv[6][r], sv[7][r]));
        lmax[r] = fmaxf(m0_, m1_);
        need |= (lmax[r] > mrun[r] + 8.f);
      }
      if (__any(need)) {
#pragma unroll
        for (int r = 0; r < 4; ++r) {
          float tm = lmax[r];
#pragma unroll
          for (int m = 1; m < 16; m <<= 1) tm = fmaxf(tm, __shfl_xor(tm, m));
          float mn = fmaxf(mrun[r], tm);
          float sc = exp2f(mrun[r] - mn);  // -inf -> 0 on first tile
          mrun[r] = mn;
          lacc[r] *= sc;
#pragma unroll
          for (int nd = 0; nd < 4; ++nd) cacc[nd][r] *= sc;
        }
      }
      // truncating P-store (bias cancels via ones-column l)
#pragma unroll
      for (int r = 0; r < 4; ++r) {
        int prow = lg * 4 + r;
        int rx = (prow & 15) << 3;
#pragma unroll
        for (int nt = 0; nt < 8; ++nt) {
          float p = exp2f(sv[nt][r] - mrun[r]);
          Ps[wv][prow][(nt * 16 + lr) ^ rx] =
              (unsigned short)(__float_as_uint(p) >> 16);
        }
      }

      // PV over 4 k-slices of 32; per-wave LDS, lgkmcnt orders
      bf16x8 pf[4];
#pragma unroll
      for (int ks = 0; ks < 4; ++ks)
        pf[ks] = *(const bf16x8*)&Ps[wv][lr][sw16(lr, ks * 32 + lg * 8)];
      __builtin_amdgcn_s_setprio(1);
#pragma unroll
      for (int ks = 0; ks < 4; ++ks)
        lacc = __builtin_amdgcn_mfma_f32_16x16x32_bf16(pf[ks], vones, lacc, 0, 0, 0);
#pragma unroll
      for (int nd = 0; nd < 4; ++nd) {
        int vrw = nd * 16 + lr;
#pragma unroll
        for (int ks = 0; ks < 4; ++ks) {
          bf16x8 vf = *(const bf16x8*)&Vs[cur][vrw][sw16(vrw, ks * 32 + lg * 8)];
          cacc[nd] = __builtin_amdgcn_mfma_f32_16x16x32_bf16(pf[ks], vf, cacc[nd], 0, 0, 0);
        }
      }
      __builtin_amdgcn_s_setprio(0);
    }

    // epilogue: l lives in lanes lr==0; broadcast within each 16-lane group
    float inv[4];
#pragma unroll
    for (int r = 0; r < 4; ++r) inv[r] = 1.f / __shfl(lacc[r], ln & 48);
#pragma unroll
    for (int nd = 0; nd < 4; ++nd)
#pragma unroll
      for (int r = 0; r < 4; ++r) {
        size_t dst = ((size_t)b * SQ + qb + wv * 16 + lg * 4 + r) * EM + h * DHD + nd * 16 + lr;
        ctx[dst] = f2bf(cacc[nd][r] * inv[r]);
      }
    if (lr == 0) {
#pragma unroll
      for (int r = 0; r < 4; ++r) {
        int row = qb + wv * 16 + lg * 4 + r;
        mstat[headoff + row] = mrun[r];            // log2 units
        lstat[headoff + row] = 0.125f * inv[r];    // 1/(H*l): attnw uses directly
      }
    }
  }
}

// ---------------- attn_weights: 2 k-tiles per block, K dbuf over heads + Q/m/l pipeline ----------------
__global__ __launch_bounds__(256) void attnw_kernel(
    const unsigned short* __restrict__ Q, const unsigned short* __restrict__ Kb,
    const float* __restrict__ mstat, const float* __restrict__ lstat,
    float* __restrict__ aw) {
  int kt2 = blockIdx.x, qt = blockIdx.y, b = blockIdx.z;
  int qb = qt * 64, kb = kt2 * 128;
  int t = threadIdx.x;
  float* tile = aw + ((size_t)b * SQ + qb) * SQ + kb;
  if (2 * kt2 > qt) {  // both 64-col tiles fully masked -> exact zeros (64x128 region)
    int row = t >> 2, cbase = (t & 3) * 32;
    f32x4 z;
#pragma unroll
    for (int j = 0; j < 4; ++j) z[j] = 0.f;
    float* p = tile + (size_t)row * SQ + cbase;
#pragma unroll
    for (int j = 0; j < 8; ++j) *(f32x4*)(p + j * 4) = z;
    return;
  }
  __shared__ unsigned short Ks[2][2][64][64];  // [dbuf][tile][kpos][dh], 32 KB
  int wv = t >> 6, ln = t & 63, lg = ln >> 4, lr = ln & 15;
  int rsub = ln >> 3;
  int csw = ((ln & 7) ^ rsub) * 8;
  size_t khstride = (size_t)SQ * DHD;
  const unsigned short* kg00 = Kb + (((size_t)b * NH) * SQ + kb + wv * 16 + rsub) * DHD + csw;
  const unsigned short* kg01 = kg00 + (size_t)8 * DHD;
  const unsigned short* kg10 = kg00 + (size_t)64 * DHD;  // second tile rows
  const unsigned short* kg11 = kg00 + (size_t)72 * DHD;
  const unsigned short* qg = Q + (((size_t)b * NH) * SQ + qb + wv * 16 + lr) * DHD + lg * 8;
  size_t mbase = (size_t)b * NH * SQ + qb + wv * 16 + lg * 4;

  // prologue: issue K head0 (both tiles) -> buf0; Q/m/l for head0 (cur) and head1 (next)
  glds16(kg00, &Ks[0][0][wv * 16][0]);
  glds16(kg01, &Ks[0][0][wv * 16 + 8][0]);
  glds16(kg10, &Ks[0][1][wv * 16][0]);
  glds16(kg11, &Ks[0][1][wv * 16 + 8][0]);

  bf16x8 aqc0 = *(const bf16x8*)qg;
  bf16x8 aqc1 = *(const bf16x8*)(qg + 32);
  bf16x8 aqn0 = *(const bf16x8*)(qg + khstride);
  bf16x8 aqn1 = *(const bf16x8*)(qg + khstride + 32);
  float mmc[4], lic[4], mmn[4], lin[4];
#pragma unroll
  for (int r = 0; r < 4; ++r) {
    mmc[r] = mstat[mbase + r];
    lic[r] = lstat[mbase + r];
    mmn[r] = mstat[mbase + SQ + r];
    lin[r] = lstat[mbase + SQ + r];
  }

  f32x4 facc[2][4];
#pragma unroll
  for (int j = 0; j < 2; ++j)
#pragma unroll
    for (int nt = 0; nt < 4; ++nt)
#pragma unroll
      for (int r = 0; r < 4; ++r) facc[j][nt][r] = 0.f;

  for (int h = 0; h < NH; ++h) {
    int cur = h & 1;
    __syncthreads();  // drains glds -> Ks[cur] ready
    if (h + 1 < NH) {  // issue next head's K (both tiles) into alternate buffer
      size_t ho = (size_t)(h + 1) * khstride;
      glds16(kg00 + ho, &Ks[cur ^ 1][0][wv * 16][0]);
      glds16(kg01 + ho, &Ks[cur ^ 1][0][wv * 16 + 8][0]);
      glds16(kg10 + ho, &Ks[cur ^ 1][1][wv * 16][0]);
      glds16(kg11 + ho, &Ks[cur ^ 1][1][wv * 16 + 8][0]);
    }

    // compute head h: both tiles with shared Q (no masking here)
#pragma unroll
    for (int nt = 0; nt < 4; ++nt) {
      int brw = nt * 16 + lr;
      f32x4 sf0, sf1;
#pragma unroll
      for (int r = 0; r < 4; ++r) { sf0[r] = 0.f; sf1[r] = 0.f; }
      bf16x8 bk00 = *(const bf16x8*)&Ks[cur][0][brw][sw8(brw, lg * 8)];
      bf16x8 bk01 = *(const bf16x8*)&Ks[cur][0][brw][sw8(brw, 32 + lg * 8)];
      bf16x8 bk10 = *(const bf16x8*)&Ks[cur][1][brw][sw8(brw, lg * 8)];
      bf16x8 bk11 = *(const bf16x8*)&Ks[cur][1][brw][sw8(brw, 32 + lg * 8)];
      sf0 = __builtin_amdgcn_mfma_f32_16x16x32_bf16(aqc0, bk00, sf0, 0, 0, 0);
      sf1 = __builtin_amdgcn_mfma_f32_16x16x32_bf16(aqc0, bk10, sf1, 0, 0, 0);
      sf0 = __builtin_amdgcn_mfma_f32_16x16x32_bf16(aqc1, bk01, sf0, 0, 0, 0);
      sf1 = __builtin_amdgcn_mfma_f32_16x16x32_bf16(aqc1, bk11, sf1, 0, 0, 0);
#pragma unroll
      for (int r = 0; r < 4; ++r) {
        facc[0][nt][r] += exp2f(sf0[r] - mmc[r]) * lic[r];
        facc[1][nt][r] += exp2f(sf1[r] - mmc[r]) * lic[r];
      }
    }

    // rotate Q/m/l pipeline; issue loads for head h+2
    aqc0 = aqn0; aqc1 = aqn1;
#pragma unroll
    for (int r = 0; r < 4; ++r) { mmc[r] = mmn[r]; lic[r] = lin[r]; }
    if (h + 2 < NH) {
      aqn0 = *(const bf16x8*)(qg + (size_t)(h + 2) * khstride);
      aqn1 = *(const bf16x8*)(qg + (size_t)(h + 2) * khstride + 32);
#pragma unroll
      for (int r = 0; r < 4; ++r) {
        mmn[r] = mstat[mbase + (size_t)(h + 2) * SQ + r];
        lin[r] = lstat[mbase + (size_t)(h + 2) * SQ + r];
      }
    }
  }

  // write; masking applied once per tile: full-mask / diagonal / none
#pragma unroll
  for (int j = 0; j < 2; ++j) {
    int ktj = 2 * kt2 + j;
    bool fullmask = (ktj > qt);
    bool dg = (ktj == qt);
#pragma unroll
    for (int nt = 0; nt < 4; ++nt) {
      int kc = kb + j * 64 + nt * 16 + lr;
#pragma unroll
      for (int r = 0; r < 4; ++r) {
        int qr = qb + wv * 16 + lg * 4 + r;
        float v = (fullmask || (dg && kc > qr)) ? 0.f : facc[j][nt][r];
        tile[(size_t)(wv * 16 + lg * 4 + r) * SQ + j * 64 + nt * 16 + lr] = v;
      }
    }
  }
}

extern "C" void kernel_launch(void* const* d_in, const int* in_sizes, int n_in,
                              void* d_out, int out_size, void* d_ws, size_t ws_size,
                              hipStream_t stream) {
  (void)in_sizes; (void)n_in; (void)out_size; (void)ws_size;
  const float* x = (const float*)d_in[0];
  const float* ln1g = (const float*)d_in[1];
  const float* ln1b = (const float*)d_in[2];
  const float* wqkv = (const float*)d_in[3];
  const float* bqkv = (const float*)d_in[4];
  const float* wout = (const float*)d_in[5];
  const float* bout = (const float*)d_in[6];
  const float* ln2g = (const float*)d_in[7];
  const float* ln2b = (const float*)d_in[8];
  const float* wfc1 = (const float*)d_in[9];
  const float* bfc1 = (const float*)d_in[10];
  const float* wfc2 = (const float*)d_in[11];
  const float* bfc2 = (const float*)d_in[12];

  char* ws = (char*)d_ws;
  unsigned short* zctx = (unsigned short*)(ws);               // z (bf16), later reused as ctx
  unsigned short* qb_ = (unsigned short*)(ws + 8388608);      // later reused as LN2 out
  unsigned short* kb_ = (unsigned short*)(ws + 16777216);     // later reused as fc1 out
  unsigned short* vb_ = (unsigned short*)(ws + 25165824);     // V^T [b,h,d,s]
  float* z2 = (float*)(ws + 33554432);                        // fp32 residual stream
  float* mstat = (float*)(ws + 50331648);
  float* lstat = (float*)(ws + 50593792);
  unsigned short* wqkv_h = (unsigned short*)(ws + 50855936);
  unsigned short* wout_h = (unsigned short*)(ws + 52428800);
  unsigned short* wfc1_h = (unsigned short*)(ws + 52953088);
  unsigned short* wfc2_h = (unsigned short*)(ws + 53477376);
  unsigned short* y1 = qb_;
  unsigned short* h1 = kb_;

  float* outy = (float*)d_out;
  float* outw = outy + (size_t)NB * SQ * EM;

  f2bf4_kernel<<<768, 256, 0, stream>>>(wqkv, wout, wfc1, wfc2,
                                        wqkv_h, wout_h, wfc1_h, wfc2_h);

  ln_kernel<<<2048, 256, 0, stream>>>(x, ln1g, ln1b, zctx);
  gemm128<true><<<dim3(64, 12), 256, 0, stream>>>(
      zctx, wqkv_h, bqkv, qb_, kb_, vb_, 8192, 1536, 512);
  flash_kernel<<<dim3(16, 8, 4), 256, 0, stream>>>(qb_, kb_, vb_, zctx, mstat, lstat);
  attnw_kernel<<<dim3(16, 32, 4), 256, 0, stream>>>(qb_, kb_, mstat, lstat, outw);
  gemm64<false, true, true, false><<<dim3(128, 8), 256, 0, stream>>>(
      zctx, wout_h, bout, x, z2, nullptr, nullptr, nullptr, nullptr, 8192, 512, 512);
  ln_kernel<<<2048, 256, 0, stream>>>(z2, ln2g, ln2b, y1);
  gemm64<true, false, false, false><<<dim3(128, 8), 256, 0, stream>>>(
      y1, wfc1_h, bfc1, nullptr, nullptr, h1, nullptr, nullptr, nullptr, 8192, 512, 512);
  gemm64<false, true, true, false><<<dim3(128, 8), 256, 0, stream>>>(
      h1, wfc2_h, bfc2, z2, outy, nullptr, nullptr, nullptr, nullptr, 8192, 512, 512);
}

// Round 19
// 176.096 us; speedup vs baseline: 1.1920x; 1.0495x over previous
//
#include <hip/hip_runtime.h>

typedef short bf16x8 __attribute__((ext_vector_type(8)));
typedef float f32x4 __attribute__((ext_vector_type(4)));
typedef unsigned short u16x8 __attribute__((ext_vector_type(8)));

#define NB 4
#define SQ 2048
#define EM 512
#define NH 8
#define DHD 64
// 1/sqrt(DH) * log2(e): Q pre-scaled so softmax uses exp2
#define QSCALE 0.1803368801111731f

__device__ __forceinline__ unsigned short f2bf(float x) {
  unsigned u = __float_as_uint(x);
  u += 0x7FFFu + ((u >> 16) & 1u);
  return (unsigned short)(u >> 16);
}

__device__ __forceinline__ int sw8(int row, int col8) { return col8 ^ ((row & 7) << 3); }
__device__ __forceinline__ int sw16(int row, int col8) { return col8 ^ ((row & 15) << 3); }

// async global->LDS, 16B/lane; LDS dest = wave-uniform base + lane*16 (linear).
// Swizzled storage achieved by pre-swizzling the per-lane GLOBAL source address.
__device__ __forceinline__ void glds16(const void* g, void* l) {
  __builtin_amdgcn_global_load_lds(
      (const __attribute__((address_space(1))) void*)g,
      (__attribute__((address_space(3))) void*)l, 16, 0, 0);
}

// ---------------- fused fp32 -> bf16 convert (all 4 weight tensors) ----------------
__global__ __launch_bounds__(256) void f2bf4_kernel(
    const float* __restrict__ w0, const float* __restrict__ w1,
    const float* __restrict__ w2, const float* __restrict__ w3,
    unsigned short* __restrict__ o0, unsigned short* __restrict__ o1,
    unsigned short* __restrict__ o2, unsigned short* __restrict__ o3) {
  int i = (blockIdx.x * 256 + threadIdx.x) * 8;
  const float* src;
  unsigned short* dst;
  int off;
  if (i < 786432) { src = w0; dst = o0; off = i; }
  else if (i < 1048576) { src = w1; dst = o1; off = i - 786432; }
  else if (i < 1310720) { src = w2; dst = o2; off = i - 1048576; }
  else { src = w3; dst = o3; off = i - 1310720; }
  f32x4 a = *(const f32x4*)(src + off);
  f32x4 b = *(const f32x4*)(src + off + 4);
  u16x8 o;
#pragma unroll
  for (int j = 0; j < 4; ++j) { o[j] = f2bf(a[j]); o[j + 4] = f2bf(b[j]); }
  *(u16x8*)(dst + off) = o;
}

// ---------------- LayerNorm (row = E=512), fp32 in -> bf16 out ----------------
__global__ __launch_bounds__(256) void ln_kernel(const float* __restrict__ x,
                                                 const float* __restrict__ g,
                                                 const float* __restrict__ bb,
                                                 unsigned short* __restrict__ out) {
  int tid = threadIdx.x;
  int row = blockIdx.x * 4 + (tid >> 6);
  int lane = tid & 63;
  size_t base = (size_t)row * EM + lane * 8;
  f32x4 v0 = *(const f32x4*)(x + base);
  f32x4 v1 = *(const f32x4*)(x + base + 4);
  float s = 0.f, q = 0.f;
#pragma unroll
  for (int j = 0; j < 4; ++j) { s += v0[j] + v1[j]; q += v0[j] * v0[j] + v1[j] * v1[j]; }
#pragma unroll
  for (int m = 1; m < 64; m <<= 1) { s += __shfl_xor(s, m); q += __shfl_xor(q, m); }
  float mean = s * (1.f / EM);
  float var = q * (1.f / EM) - mean * mean;
  float rs = rsqrtf(var + 1e-5f);
  f32x4 g0 = *(const f32x4*)(g + lane * 8), g1 = *(const f32x4*)(g + lane * 8 + 4);
  f32x4 b0 = *(const f32x4*)(bb + lane * 8), b1 = *(const f32x4*)(bb + lane * 8 + 4);
  u16x8 o;
#pragma unroll
  for (int j = 0; j < 4; ++j) {
    o[j] = f2bf((v0[j] - mean) * rs * g0[j] + b0[j]);
    o[j + 4] = f2bf((v1[j] - mean) * rs * g1[j] + b1[j]);
  }
  *(u16x8*)(out + base) = o;
}

// ---------------- GEMM 64x64: dbuf LDS via global_load_lds (1 barrier/iter) ----------------
template <bool LEAKY, bool RESID, bool OUTF32, bool QKV>
__global__ __launch_bounds__(256) void gemm64(
    const unsigned short* __restrict__ A, const unsigned short* __restrict__ Bm,
    const float* __restrict__ bias, const float* __restrict__ resid,
    float* __restrict__ outf, unsigned short* __restrict__ outh,
    unsigned short* __restrict__ qo, unsigned short* __restrict__ ko,
    unsigned short* __restrict__ vo, int M, int N, int K) {
  __shared__ unsigned short As[2][64][64];
  __shared__ unsigned short Bs[2][64][64];
  int m0 = blockIdx.x * 64, n0 = blockIdx.y * 64;
  int t = threadIdx.x;
  int wv = t >> 6, ln = t & 63, lg = ln >> 4, lr = ln & 15;
  int rsub = ln >> 3;
  int csw = ((ln & 7) ^ rsub) * 8;
  f32x4 acc[4];
#pragma unroll
  for (int c = 0; c < 4; ++c)
#pragma unroll
    for (int r = 0; r < 4; ++r) acc[c][r] = 0.f;

  const unsigned short* ag0 = A + (size_t)(m0 + wv * 16 + rsub) * K + csw;
  const unsigned short* ag1 = A + (size_t)(m0 + wv * 16 + 8 + rsub) * K + csw;
  const unsigned short* bg0 = Bm + (size_t)(n0 + wv * 16 + rsub) * K + csw;
  const unsigned short* bg1 = Bm + (size_t)(n0 + wv * 16 + 8 + rsub) * K + csw;

  glds16(ag0, &As[0][wv * 16][0]);
  glds16(ag1, &As[0][wv * 16 + 8][0]);
  glds16(bg0, &Bs[0][wv * 16][0]);
  glds16(bg1, &Bs[0][wv * 16 + 8][0]);

  int nk = K >> 6;
  for (int ki = 0; ki < nk; ++ki) {
    int cur = ki & 1;
    __syncthreads();
    if (ki + 1 < nk) {
      int nb = cur ^ 1;
      int ko_ = (ki + 1) * 64;
      glds16(ag0 + ko_, &As[nb][wv * 16][0]);
      glds16(ag1 + ko_, &As[nb][wv * 16 + 8][0]);
      glds16(bg0 + ko_, &Bs[nb][wv * 16][0]);
      glds16(bg1 + ko_, &Bs[nb][wv * 16 + 8][0]);
    }
#pragma unroll
    for (int kk = 0; kk < 64; kk += 32) {
      int arw = wv * 16 + lr;
      bf16x8 af = *(const bf16x8*)&As[cur][arw][sw8(arw, kk + lg * 8)];
#pragma unroll
      for (int c = 0; c < 4; ++c) {
        int brw = c * 16 + lr;
        bf16x8 bf = *(const bf16x8*)&Bs[cur][brw][sw8(brw, kk + lg * 8)];
        acc[c] = __builtin_amdgcn_mfma_f32_16x16x32_bf16(af, bf, acc[c], 0, 0, 0);
      }
    }
  }
#pragma unroll
  for (int c = 0; c < 4; ++c) {
    int C_ = n0 + c * 16 + lr;
    float bv = bias[C_];
#pragma unroll
    for (int r = 0; r < 4; ++r) {
      int R_ = m0 + wv * 16 + lg * 4 + r;
      float v = acc[c][r] + bv;
      if (LEAKY) v = v > 0.f ? v : 0.01f * v;
      if (RESID) v += resid[(size_t)R_ * N + C_];
      if (QKV) {
        int which = C_ >> 9, f = C_ & 511, h = f >> 6, d = f & 63;
        int b_ = R_ >> 11, s_ = R_ & 2047;
        if (which == 0) {
          qo[(((size_t)b_ * NH + h) * SQ + s_) * DHD + d] = f2bf(v * QSCALE);
        } else if (which == 1) {
          ko[(((size_t)b_ * NH + h) * SQ + s_) * DHD + d] = f2bf(v);
        } else {
          vo[(((size_t)b_ * NH + h) * DHD + d) * SQ + s_] = f2bf(v);  // V^T [b,h,d,s]
        }
      } else if (OUTF32) {
        outf[(size_t)R_ * N + C_] = v;
      } else {
        outh[(size_t)R_ * N + C_] = f2bf(v);
      }
    }
  }
}

// ---------------- GEMM 128x128 (QKV only): dbuf LDS via glds, 2x2 wave quadrants ----------------
template <bool QKV>
__global__ __launch_bounds__(256) void gemm128(
    const unsigned short* __restrict__ A, const unsigned short* __restrict__ Bm,
    const float* __restrict__ bias, unsigned short* __restrict__ qo,
    unsigned short* __restrict__ ko, unsigned short* __restrict__ vo,
    int M, int N, int K) {
  __shared__ unsigned short As[2][128][64];
  __shared__ unsigned short Bs[2][128][64];
  int m0 = blockIdx.x * 128, n0 = blockIdx.y * 128;
  int t = threadIdx.x;
  int wv = t >> 6, ln = t & 63, lg = ln >> 4, lr = ln & 15;
  int wr = wv >> 1, wc = wv & 1;
  int rsub = ln >> 3;
  int csw = ((ln & 7) ^ rsub) * 8;
  f32x4 acc[4][4];
#pragma unroll
  for (int m = 0; m < 4; ++m)
#pragma unroll
    for (int n = 0; n < 4; ++n)
#pragma unroll
      for (int r = 0; r < 4; ++r) acc[m][n][r] = 0.f;

  const unsigned short* agb = A + (size_t)(m0 + wv * 8 + rsub) * K + csw;
  const unsigned short* bgb = Bm + (size_t)(n0 + wv * 8 + rsub) * K + csw;

#pragma unroll
  for (int i = 0; i < 4; ++i) {
    glds16(agb + (size_t)(i * 32) * K, &As[0][i * 32 + wv * 8][0]);
    glds16(bgb + (size_t)(i * 32) * K, &Bs[0][i * 32 + wv * 8][0]);
  }

  int nk = K >> 6;
  for (int ki = 0; ki < nk; ++ki) {
    int cur = ki & 1;
    __syncthreads();
    if (ki + 1 < nk) {
      int nb = cur ^ 1;
      int ko_ = (ki + 1) * 64;
#pragma unroll
      for (int i = 0; i < 4; ++i) {
        glds16(agb + (size_t)(i * 32) * K + ko_, &As[nb][i * 32 + wv * 8][0]);
        glds16(bgb + (size_t)(i * 32) * K + ko_, &Bs[nb][i * 32 + wv * 8][0]);
      }
    }
#pragma unroll
    for (int kk = 0; kk < 64; kk += 32) {
      bf16x8 af[4], bfr[4];
#pragma unroll
      for (int m = 0; m < 4; ++m) {
        int arw = wr * 64 + m * 16 + lr;
        af[m] = *(const bf16x8*)&As[cur][arw][sw8(arw, kk + lg * 8)];
      }
#pragma unroll
      for (int n = 0; n < 4; ++n) {
        int brw = wc * 64 + n * 16 + lr;
        bfr[n] = *(const bf16x8*)&Bs[cur][brw][sw8(brw, kk + lg * 8)];
      }
#pragma unroll
      for (int m = 0; m < 4; ++m)
#pragma unroll
        for (int n = 0; n < 4; ++n)
          acc[m][n] = __builtin_amdgcn_mfma_f32_16x16x32_bf16(af[m], bfr[n], acc[m][n], 0, 0, 0);
    }
  }

#pragma unroll
  for (int n = 0; n < 4; ++n) {
    int C_ = n0 + wc * 64 + n * 16 + lr;
    float bv = bias[C_];
#pragma unroll
    for (int m = 0; m < 4; ++m) {
#pragma unroll
      for (int r = 0; r < 4; ++r) {
        int R_ = m0 + wr * 64 + m * 16 + lg * 4 + r;
        float v = acc[m][n][r] + bv;
        int which = C_ >> 9, f = C_ & 511, h = f >> 6, d = f & 63;
        int b_ = R_ >> 11, s_ = R_ & 2047;
        if (which == 0) {
          qo[(((size_t)b_ * NH + h) * SQ + s_) * DHD + d] = f2bf(v * QSCALE);
        } else if (which == 1) {
          ko[(((size_t)b_ * NH + h) * SQ + s_) * DHD + d] = f2bf(v);
        } else {
          vo[(((size_t)b_ * NH + h) * DHD + d) * SQ + s_] = f2bf(v);  // V^T [b,h,d,s]
        }
      }
    }
  }
}

// ---------------- Flash attention: KVBLK=128, paired q-tiles, XCD-swizzled 1D grid ----------------
// lin -> xcd = lin&7; each XCD owns 4 complete (b,h) groups so K/V stays L2-resident.
__global__ __launch_bounds__(256) void flash_kernel(
    const unsigned short* __restrict__ Q, const unsigned short* __restrict__ Kb,
    const unsigned short* __restrict__ Vt, unsigned short* __restrict__ ctx,
    float* __restrict__ mstat, float* __restrict__ lstat) {
  __shared__ unsigned short Ks[2][128][64];   // [buf][kpos][dh], sw8-swizzled
  __shared__ unsigned short Vs[2][64][128];   // [buf][dh][kpos], sw16-swizzled
  __shared__ unsigned short Ps[4][16][128];   // per-wave P [q][kpos], sw16-swizzled
  int lin = blockIdx.x;
  int xcd = lin & 7, slot = lin >> 3;          // slot 0..63
  int grp = xcd + 8 * (slot >> 4);             // (b,h) group 0..31, 4 per XCD
  int bxp = slot & 15;                          // paired q-index 0..15
  int h = grp & 7, b = grp >> 3;
  int t = threadIdx.x, wv = t >> 6, ln = t & 63, lg = ln >> 4, lr = ln & 15;
  size_t headoff = ((size_t)b * NH + h) * SQ;
  size_t vbase = ((size_t)b * NH + h) * DHD;

  // K staging: 4 glds/wave, rows wv*32+g*8+(ln>>3); src pre-swizzle (ln&7)^(ln>>3)
  int cswK = ((ln & 7) ^ (ln >> 3)) * 8;
  const unsigned short* kgb = Kb + (headoff + wv * 32 + (ln >> 3)) * DHD + cswK;
  // V staging: 4 glds/wave, d-rows wv*16+g*4+(ln>>4); src pre-swizzle (ln&15)^(g*4+(ln>>4))
  int vrow4 = ln >> 4;  // 0..3
  const unsigned short* vgb = Vt + (vbase + wv * 16 + vrow4) * SQ;
  int vcsw[4];
#pragma unroll
  for (int g = 0; g < 4; ++g) vcsw[g] = ((ln & 15) ^ (g * 4 + vrow4)) * 8;

  // ones B-fragment: accumulator col 0 = row-sum of P
  bf16x8 vones;
#pragma unroll
  for (int j = 0; j < 8; ++j) vones[j] = (lr == 0) ? (short)0x3F80 : (short)0;

  for (int half = 0; half < 2; ++half) {
    int qt = half ? bxp : (31 - bxp);  // heavy half first
    int qb = qt * 64;
    const unsigned short* qrow = Q + (headoff + qb + wv * 16 + lr) * DHD;
    bf16x8 aq0 = *(const bf16x8*)(qrow + lg * 8);
    bf16x8 aq1 = *(const bf16x8*)(qrow + 32 + lg * 8);

    f32x4 cacc[4], lacc;
#pragma unroll
    for (int nd = 0; nd < 4; ++nd)
#pragma unroll
      for (int r = 0; r < 4; ++r) cacc[nd][r] = 0.f;
#pragma unroll
    for (int r = 0; r < 4; ++r) lacc[r] = 0.f;
    float mrun[4];
#pragma unroll
    for (int r = 0; r < 4; ++r) mrun[r] = -__builtin_inff();

    int nkt = (qt + 2) >> 1;  // 128-wide k-tiles covering rows 0..qb+63
    __syncthreads();  // previous half's LDS reads fully done
    // prologue: issue tile 0 into buf0 (8 glds/wave)
#pragma unroll
    for (int g = 0; g < 4; ++g) {
      glds16(kgb + (size_t)(g * 8) * DHD, &Ks[0][wv * 32 + g * 8][0]);
      glds16(vgb + (size_t)(g * 4) * SQ + vcsw[g], &Vs[0][wv * 16 + g * 4][0]);
    }

    for (int kt = 0; kt < nkt; ++kt) {
      int cur = kt & 1;
      int kb = kt * 128;
      __syncthreads();  // drains glds -> buf[cur] ready
      if (kt + 1 < nkt) {  // issue next tile into alternate buffer
        int nb = cur ^ 1;
        size_t ko_ = (size_t)(kt + 1) * 128;
#pragma unroll
        for (int g = 0; g < 4; ++g) {
          glds16(kgb + (ko_ + g * 8) * DHD, &Ks[nb][wv * 32 + g * 8][0]);
          glds16(vgb + (size_t)(g * 4) * SQ + ko_ + vcsw[g], &Vs[nb][wv * 16 + g * 4][0]);
        }
      }

      // QK^T over 128 cols (Q pre-scaled; scores in log2 units)
      float sv[8][4];
      __builtin_amdgcn_s_setprio(1);
#pragma unroll
      for (int nt = 0; nt < 8; ++nt) {
        f32x4 sf;
#pragma unroll
        for (int r = 0; r < 4; ++r) sf[r] = 0.f;
        int brw = nt * 16 + lr;
        bf16x8 bk0 = *(const bf16x8*)&Ks[cur][brw][sw8(brw, lg * 8)];
        bf16x8 bk1 = *(const bf16x8*)&Ks[cur][brw][sw8(brw, 32 + lg * 8)];
        sf = __builtin_amdgcn_mfma_f32_16x16x32_bf16(aq0, bk0, sf, 0, 0, 0);
        sf = __builtin_amdgcn_mfma_f32_16x16x32_bf16(aq1, bk1, sf, 0, 0, 0);
#pragma unroll
        for (int r = 0; r < 4; ++r) sv[nt][r] = sf[r];
      }
      __builtin_amdgcn_s_setprio(0);
      if (kt == nkt - 1) {  // tile containing the diagonal: causal mask
#pragma unroll
        for (int nt = 0; nt < 8; ++nt) {
          int kcol = kb + nt * 16 + lr;
#pragma unroll
          for (int r = 0; r < 4; ++r) {
            int qr = qb + wv * 16 + lg * 4 + r;
            if (kcol > qr) sv[nt][r] = -__builtin_inff();
          }
        }
      }

      // online softmax over 128 cols: lane-local defer-max gate
      float lmax[4];
      bool need = false;
#pragma unroll
      for (int r = 0; r < 4; ++r) {
        float m0_ = fmaxf(fmaxf(sv[0][r], sv[1][r]), fmaxf(sv[2][r], sv[3][r]));
        float m1_ = fmaxf(fmaxf(sv[4][r], sv[5][r]), fmaxf(sv[6][r], sv[7][r]));
        lmax[r] = fmaxf(m0_, m1_);
        need |= (lmax[r] > mrun[r] + 8.f);
      }
      if (__any(need)) {
#pragma unroll
        for (int r = 0; r < 4; ++r) {
          float tm = lmax[r];
#pragma unroll
          for (int m = 1; m < 16; m <<= 1) tm = fmaxf(tm, __shfl_xor(tm, m));
          float mn = fmaxf(mrun[r], tm);
          float sc = exp2f(mrun[r] - mn);  // -inf -> 0 on first tile
          mrun[r] = mn;
          lacc[r] *= sc;
#pragma unroll
          for (int nd = 0; nd < 4; ++nd) cacc[nd][r] *= sc;
        }
      }
      // truncating P-store (bias cancels via ones-column l)
#pragma unroll
      for (int r = 0; r < 4; ++r) {
        int prow = lg * 4 + r;
        int rx = (prow & 15) << 3;
#pragma unroll
        for (int nt = 0; nt < 8; ++nt) {
          float p = exp2f(sv[nt][r] - mrun[r]);
          Ps[wv][prow][(nt * 16 + lr) ^ rx] =
              (unsigned short)(__float_as_uint(p) >> 16);
        }
      }

      // PV over 4 k-slices of 32; per-wave LDS, lgkmcnt orders
      bf16x8 pf[4];
#pragma unroll
      for (int ks = 0; ks < 4; ++ks)
        pf[ks] = *(const bf16x8*)&Ps[wv][lr][sw16(lr, ks * 32 + lg * 8)];
      __builtin_amdgcn_s_setprio(1);
#pragma unroll
      for (int ks = 0; ks < 4; ++ks)
        lacc = __builtin_amdgcn_mfma_f32_16x16x32_bf16(pf[ks], vones, lacc, 0, 0, 0);
#pragma unroll
      for (int nd = 0; nd < 4; ++nd) {
        int vrw = nd * 16 + lr;
#pragma unroll
        for (int ks = 0; ks < 4; ++ks) {
          bf16x8 vf = *(const bf16x8*)&Vs[cur][vrw][sw16(vrw, ks * 32 + lg * 8)];
          cacc[nd] = __builtin_amdgcn_mfma_f32_16x16x32_bf16(pf[ks], vf, cacc[nd], 0, 0, 0);
        }
      }
      __builtin_amdgcn_s_setprio(0);
    }

    // epilogue: l lives in lanes lr==0; broadcast within each 16-lane group
    float inv[4];
#pragma unroll
    for (int r = 0; r < 4; ++r) inv[r] = 1.f / __shfl(lacc[r], ln & 48);
#pragma unroll
    for (int nd = 0; nd < 4; ++nd)
#pragma unroll
      for (int r = 0; r < 4; ++r) {
        size_t dst = ((size_t)b * SQ + qb + wv * 16 + lg * 4 + r) * EM + h * DHD + nd * 16 + lr;
        ctx[dst] = f2bf(cacc[nd][r] * inv[r]);
      }
    if (lr == 0) {
#pragma unroll
      for (int r = 0; r < 4; ++r) {
        int row = qb + wv * 16 + lg * 4 + r;
        mstat[headoff + row] = mrun[r];            // log2 units
        lstat[headoff + row] = 0.125f * inv[r];    // 1/(H*l): attnw uses directly
      }
    }
  }
}

// ---------------- attn_weights: 2 k-tiles per block, XCD-swizzled 1D grid ----------------
// lin -> xcd = lin&7; each XCD owns 8 (b,kt2) combos so the shared K panel stays L2-resident.
__global__ __launch_bounds__(256) void attnw_kernel(
    const unsigned short* __restrict__ Q, const unsigned short* __restrict__ Kb,
    const float* __restrict__ mstat, const float* __restrict__ lstat,
    float* __restrict__ aw) {
  int lin = blockIdx.x;
  int xcd = lin & 7, slot = lin >> 3;          // slot 0..255
  int combo = xcd + 8 * (slot >> 5);           // (b,kt2) combo 0..63, 8 per XCD
  int qt = slot & 31;
  int kt2 = combo & 15, b = combo >> 4;
  int qb = qt * 64, kb = kt2 * 128;
  int t = threadIdx.x;
  float* tile = aw + ((size_t)b * SQ + qb) * SQ + kb;
  if (2 * kt2 > qt) {  // both 64-col tiles fully masked -> exact zeros (64x128 region)
    int row = t >> 2, cbase = (t & 3) * 32;
    f32x4 z;
#pragma unroll
    for (int j = 0; j < 4; ++j) z[j] = 0.f;
    float* p = tile + (size_t)row * SQ + cbase;
#pragma unroll
    for (int j = 0; j < 8; ++j) *(f32x4*)(p + j * 4) = z;
    return;
  }
  __shared__ unsigned short Ks[2][2][64][64];  // [dbuf][tile][kpos][dh], 32 KB
  int wv = t >> 6, ln = t & 63, lg = ln >> 4, lr = ln & 15;
  int rsub = ln >> 3;
  int csw = ((ln & 7) ^ rsub) * 8;
  size_t khstride = (size_t)SQ * DHD;
  const unsigned short* kg00 = Kb + (((size_t)b * NH) * SQ + kb + wv * 16 + rsub) * DHD + csw;
  const unsigned short* kg01 = kg00 + (size_t)8 * DHD;
  const unsigned short* kg10 = kg00 + (size_t)64 * DHD;  // second tile rows
  const unsigned short* kg11 = kg00 + (size_t)72 * DHD;
  const unsigned short* qg = Q + (((size_t)b * NH) * SQ + qb + wv * 16 + lr) * DHD + lg * 8;
  size_t mbase = (size_t)b * NH * SQ + qb + wv * 16 + lg * 4;

  // prologue: issue K head0 (both tiles) -> buf0; Q/m/l for head0 (cur) and head1 (next)
  glds16(kg00, &Ks[0][0][wv * 16][0]);
  glds16(kg01, &Ks[0][0][wv * 16 + 8][0]);
  glds16(kg10, &Ks[0][1][wv * 16][0]);
  glds16(kg11, &Ks[0][1][wv * 16 + 8][0]);

  bf16x8 aqc0 = *(const bf16x8*)qg;
  bf16x8 aqc1 = *(const bf16x8*)(qg + 32);
  bf16x8 aqn0 = *(const bf16x8*)(qg + khstride);
  bf16x8 aqn1 = *(const bf16x8*)(qg + khstride + 32);
  float mmc[4], lic[4], mmn[4], lin_[4];
#pragma unroll
  for (int r = 0; r < 4; ++r) {
    mmc[r] = mstat[mbase + r];
    lic[r] = lstat[mbase + r];
    mmn[r] = mstat[mbase + SQ + r];
    lin_[r] = lstat[mbase + SQ + r];
  }

  f32x4 facc[2][4];
#pragma unroll
  for (int j = 0; j < 2; ++j)
#pragma unroll
    for (int nt = 0; nt < 4; ++nt)
#pragma unroll
      for (int r = 0; r < 4; ++r) facc[j][nt][r] = 0.f;

  for (int h = 0; h < NH; ++h) {
    int cur = h & 1;
    __syncthreads();  // drains glds -> Ks[cur] ready
    if (h + 1 < NH) {  // issue next head's K (both tiles) into alternate buffer
      size_t ho = (size_t)(h + 1) * khstride;
      glds16(kg00 + ho, &Ks[cur ^ 1][0][wv * 16][0]);
      glds16(kg01 + ho, &Ks[cur ^ 1][0][wv * 16 + 8][0]);
      glds16(kg10 + ho, &Ks[cur ^ 1][1][wv * 16][0]);
      glds16(kg11 + ho, &Ks[cur ^ 1][1][wv * 16 + 8][0]);
    }

    // compute head h: both tiles with shared Q (no masking here)
#pragma unroll
    for (int nt = 0; nt < 4; ++nt) {
      int brw = nt * 16 + lr;
      f32x4 sf0, sf1;
#pragma unroll
      for (int r = 0; r < 4; ++r) { sf0[r] = 0.f; sf1[r] = 0.f; }
      bf16x8 bk00 = *(const bf16x8*)&Ks[cur][0][brw][sw8(brw, lg * 8)];
      bf16x8 bk01 = *(const bf16x8*)&Ks[cur][0][brw][sw8(brw, 32 + lg * 8)];
      bf16x8 bk10 = *(const bf16x8*)&Ks[cur][1][brw][sw8(brw, lg * 8)];
      bf16x8 bk11 = *(const bf16x8*)&Ks[cur][1][brw][sw8(brw, 32 + lg * 8)];
      sf0 = __builtin_amdgcn_mfma_f32_16x16x32_bf16(aqc0, bk00, sf0, 0, 0, 0);
      sf1 = __builtin_amdgcn_mfma_f32_16x16x32_bf16(aqc0, bk10, sf1, 0, 0, 0);
      sf0 = __builtin_amdgcn_mfma_f32_16x16x32_bf16(aqc1, bk01, sf0, 0, 0, 0);
      sf1 = __builtin_amdgcn_mfma_f32_16x16x32_bf16(aqc1, bk11, sf1, 0, 0, 0);
#pragma unroll
      for (int r = 0; r < 4; ++r) {
        facc[0][nt][r] += exp2f(sf0[r] - mmc[r]) * lic[r];
        facc[1][nt][r] += exp2f(sf1[r] - mmc[r]) * lic[r];
      }
    }

    // rotate Q/m/l pipeline; issue loads for head h+2
    aqc0 = aqn0; aqc1 = aqn1;
#pragma unroll
    for (int r = 0; r < 4; ++r) { mmc[r] = mmn[r]; lic[r] = lin_[r]; }
    if (h + 2 < NH) {
      aqn0 = *(const bf16x8*)(qg + (size_t)(h + 2) * khstride);
      aqn1 = *(const bf16x8*)(qg + (size_t)(h + 2) * khstride + 32);
#pragma unroll
      for (int r = 0; r < 4; ++r) {
        mmn[r] = mstat[mbase + (size_t)(h + 2) * SQ + r];
        lin_[r] = lstat[mbase + (size_t)(h + 2) * SQ + r];
      }
    }
  }

  // write; masking applied once per tile: full-mask / diagonal / none
#pragma unroll
  for (int j = 0; j < 2; ++j) {
    int ktj = 2 * kt2 + j;
    bool fullmask = (ktj > qt);
    bool dg = (ktj == qt);
#pragma unroll
    for (int nt = 0; nt < 4; ++nt) {
      int kc = kb + j * 64 + nt * 16 + lr;
#pragma unroll
      for (int r = 0; r < 4; ++r) {
        int qr = qb + wv * 16 + lg * 4 + r;
        float v = (fullmask || (dg && kc > qr)) ? 0.f : facc[j][nt][r];
        tile[(size_t)(wv * 16 + lg * 4 + r) * SQ + j * 64 + nt * 16 + lr] = v;
      }
    }
  }
}

extern "C" void kernel_launch(void* const* d_in, const int* in_sizes, int n_in,
                              void* d_out, int out_size, void* d_ws, size_t ws_size,
                              hipStream_t stream) {
  (void)in_sizes; (void)n_in; (void)out_size; (void)ws_size;
  const float* x = (const float*)d_in[0];
  const float* ln1g = (const float*)d_in[1];
  const float* ln1b = (const float*)d_in[2];
  const float* wqkv = (const float*)d_in[3];
  const float* bqkv = (const float*)d_in[4];
  const float* wout = (const float*)d_in[5];
  const float* bout = (const float*)d_in[6];
  const float* ln2g = (const float*)d_in[7];
  const float* ln2b = (const float*)d_in[8];
  const float* wfc1 = (const float*)d_in[9];
  const float* bfc1 = (const float*)d_in[10];
  const float* wfc2 = (const float*)d_in[11];
  const float* bfc2 = (const float*)d_in[12];

  char* ws = (char*)d_ws;
  unsigned short* zctx = (unsigned short*)(ws);               // z (bf16), later reused as ctx
  unsigned short* qb_ = (unsigned short*)(ws + 8388608);      // later reused as LN2 out
  unsigned short* kb_ = (unsigned short*)(ws + 16777216);     // later reused as fc1 out
  unsigned short* vb_ = (unsigned short*)(ws + 25165824);     // V^T [b,h,d,s]
  float* z2 = (float*)(ws + 33554432);                        // fp32 residual stream
  float* mstat = (float*)(ws + 50331648);
  float* lstat = (float*)(ws + 50593792);
  unsigned short* wqkv_h = (unsigned short*)(ws + 50855936);
  unsigned short* wout_h = (unsigned short*)(ws + 52428800);
  unsigned short* wfc1_h = (unsigned short*)(ws + 52953088);
  unsigned short* wfc2_h = (unsigned short*)(ws + 53477376);
  unsigned short* y1 = qb_;
  unsigned short* h1 = kb_;

  float* outy = (float*)d_out;
  float* outw = outy + (size_t)NB * SQ * EM;

  f2bf4_kernel<<<768, 256, 0, stream>>>(wqkv, wout, wfc1, wfc2,
                                        wqkv_h, wout_h, wfc1_h, wfc2_h);

  ln_kernel<<<2048, 256, 0, stream>>>(x, ln1g, ln1b, zctx);
  gemm128<true><<<dim3(64, 12), 256, 0, stream>>>(
      zctx, wqkv_h, bqkv, qb_, kb_, vb_, 8192, 1536, 512);
  flash_kernel<<<512, 256, 0, stream>>>(qb_, kb_, vb_, zctx, mstat, lstat);
  attnw_kernel<<<2048, 256, 0, stream>>>(qb_, kb_, mstat, lstat, outw);
  gemm64<false, true, true, false><<<dim3(128, 8), 256, 0, stream>>>(
      zctx, wout_h, bout, x, z2, nullptr, nullptr, nullptr, nullptr, 8192, 512, 512);
  ln_kernel<<<2048, 256, 0, stream>>>(z2, ln2g, ln2b, y1);
  gemm64<true, false, false, false><<<dim3(128, 8), 256, 0, stream>>>(
      y1, wfc1_h, bfc1, nullptr, nullptr, h1, nullptr, nullptr, nullptr, 8192, 512, 512);
  gemm64<false, true, true, false><<<dim3(128, 8), 256, 0, stream>>>(
      h1, wfc2_h, bfc2, z2, outy, nullptr, nullptr, nullptr, nullptr, 8192, 512, 512);
}